// Round 4
// baseline (854.263 us; speedup 1.0000x reference)
//
#include <hip/hip_runtime.h>
#include <cstdint>
#include <cstddef>

#define N_NODES 50000
#define E_EDGES 800000
#define INCH 128
#define HID 64
#define HEADS 4
#define NHD 256      // HEADS*HID
#define NGRAPH 64
#define DCAT 640     // 128 + 256 + 256
#define NEG_SLOPE 0.2f

// ---------------- GEMM: C[M,Nc] = A[M,K] @ B[K,Nc], fp32, row-major ----------
#define BM 128
#define BN 128
#define BKK 8

__global__ __launch_bounds__(256, 2) void gemm_f32(
    const float* __restrict__ A, const float* __restrict__ B,
    float* __restrict__ C, int M, int K, int Nc)
{
    __shared__ float As[BKK][BM];
    __shared__ float Bs[BKK][BN];
    const int t  = threadIdx.x;
    const int tx = t & 15, ty = t >> 4;
    const int row0 = blockIdx.x * BM;
    const int col0 = blockIdx.y * BN;

    float acc[8][8];
#pragma unroll
    for (int i = 0; i < 8; ++i)
#pragma unroll
        for (int j = 0; j < 8; ++j) acc[i][j] = 0.f;

    const int ar = t >> 1;          // 0..127
    const int ac = (t & 1) * 4;     // 0 or 4
    const int br = t >> 5;          // 0..7
    const int bc = (t & 31) * 4;    // 0..124

    for (int k0 = 0; k0 < K; k0 += BKK) {
        float4 av = make_float4(0.f, 0.f, 0.f, 0.f);
        const int arow = row0 + ar;
        if (arow < M)
            av = *(const float4*)(A + (size_t)arow * K + k0 + ac);
        As[ac + 0][ar] = av.x; As[ac + 1][ar] = av.y;
        As[ac + 2][ar] = av.z; As[ac + 3][ar] = av.w;

        float4 bv = *(const float4*)(B + (size_t)(k0 + br) * Nc + col0 + bc);
        *(float4*)(&Bs[br][bc]) = bv;
        __syncthreads();

#pragma unroll
        for (int k = 0; k < BKK; ++k) {
            float a[8], b[8];
#pragma unroll
            for (int i = 0; i < 8; ++i) a[i] = As[k][ty * 8 + i];
#pragma unroll
            for (int j = 0; j < 8; ++j) b[j] = Bs[k][tx * 8 + j];
#pragma unroll
            for (int i = 0; i < 8; ++i)
#pragma unroll
                for (int j = 0; j < 8; ++j) acc[i][j] += a[i] * b[j];
        }
        __syncthreads();
    }

#pragma unroll
    for (int i = 0; i < 8; ++i) {
        const int r = row0 + ty * 8 + i;
        if (r < M) {
            float* cp = C + (size_t)r * Nc + col0 + tx * 8;
            float4 v0 = make_float4(acc[i][0], acc[i][1], acc[i][2], acc[i][3]);
            float4 v1 = make_float4(acc[i][4], acc[i][5], acc[i][6], acc[i][7]);
            *(float4*)cp = v0;
            *(float4*)(cp + 4) = v1;
        }
    }
}

// ------------- attention coefficients: es[n,h] = <h[n,h,:], a_src[h,:]> ------
__global__ __launch_bounds__(256) void attn_coef(
    const float* __restrict__ h, const float* __restrict__ asrc,
    const float* __restrict__ adst, float* __restrict__ es, float* __restrict__ ed)
{
    const int n = blockIdx.x;
    const int t = threadIdx.x;
    const float v = h[(size_t)n * NHD + t];
    float s1 = v * asrc[t];
    float s2 = v * adst[t];
#pragma unroll
    for (int off = 32; off; off >>= 1) {
        s1 += __shfl_down(s1, off, 64);
        s2 += __shfl_down(s2, off, 64);
    }
    if ((t & 63) == 0) {
        es[n * HEADS + (t >> 6)] = s1;
        ed[n * HEADS + (t >> 6)] = s2;
    }
}

// ------------------------------ CSR build -----------------------------------
__global__ void hist_kernel(const int* __restrict__ ei, int* __restrict__ counts)
{
    const int e = blockIdx.x * 256 + threadIdx.x;
    if (e >= E_EDGES) return;
    atomicAdd(&counts[ei[E_EDGES + e]], 1);
}

// Thread-coarsened single-block exclusive scan: each thread serially scans
// SCAN_C contiguous counts in registers, one 1024-wide block scan of the
// partials (~22 barriers total vs ~980 in the naive chunked version).
// Writes offsets AND cursor (saves a copy kernel).
#define SCAN_T 1024
#define SCAN_C ((N_NODES + SCAN_T - 1) / SCAN_T)   // 49

__global__ __launch_bounds__(1024) void scan_kernel(const int* __restrict__ counts,
                                                    int* __restrict__ offsets,
                                                    int* __restrict__ cursor)
{
    __shared__ int part[SCAN_T];
    const int t  = threadIdx.x;
    const int lo = t * SCAN_C;
    const int hi = min(N_NODES, lo + SCAN_C);
    int local[SCAN_C];
    int sum = 0;
    for (int i = lo; i < hi; ++i) { local[i - lo] = sum; sum += counts[i]; }
    part[t] = sum;
    __syncthreads();
    for (int off = 1; off < SCAN_T; off <<= 1) {
        const int v = (t >= off) ? part[t - off] : 0;
        __syncthreads();
        part[t] += v;
        __syncthreads();
    }
    const int base = (t == 0) ? 0 : part[t - 1];
    for (int i = lo; i < hi; ++i) {
        const int v = base + local[i - lo];
        offsets[i] = v;
        cursor[i]  = v;
    }
    if (t == SCAN_T - 1) offsets[N_NODES] = part[SCAN_T - 1];
}

__global__ void scatter_kernel(const int* __restrict__ ei, int* __restrict__ cursor,
                               int* __restrict__ csr)
{
    const int e = blockIdx.x * 256 + threadIdx.x;
    if (e >= E_EDGES) return;
    const int d = ei[E_EDGES + e];
    const int pos = atomicAdd(&cursor[d], 1);
    csr[pos] = e;
}

// ------- fused softmax + aggregation: one wave per dst node ------------------
// 16-edge sub-chunks: lane l computes the weight for (edge = l&15,
// head = l>>4) -- one scalar es load + one exp per lane. Inner loop per edge:
// 2 shfl broadcasts + one coalesced 1KB h-row gather + 4 FMA. Softmax
// denominator accumulates in-register (no atomics, no denom array).
__global__ __launch_bounds__(256) void aggregate_fused(
    const float* __restrict__ h, const int* __restrict__ ei,
    const int* __restrict__ csr, const int* __restrict__ offsets,
    const float* __restrict__ es, const float* __restrict__ ed,
    const float* __restrict__ bias, float* __restrict__ out)
{
    const int wid  = threadIdx.x >> 6;
    const int lane = threadIdx.x & 63;
    const int node = blockIdx.x * 4 + wid;
    if (node >= N_NODES) return;
    const int head = lane >> 4;          // col = lane*4 -> head = col/64
    const int col  = lane * 4;
    const int sub  = lane & 15;          // edge slot within 16-edge chunk

    const float edc = ed[node * 4 + head];
    const int beg = offsets[node], end = offsets[node + 1];

    float4 acc = make_float4(0.f, 0.f, 0.f, 0.f);
    float dsum = 0.f;

    for (int base = beg; base < end; base += 16) {
        const int m = min(16, end - base);
        int s_l = 0; float w_l = 0.f;
        if (sub < m) {
            const int eid = csr[base + sub];
            s_l = ei[eid];
            float u = es[s_l * 4 + head] + edc;
            u = u > 0.f ? u : NEG_SLOPE * u;
            w_l = expf(u);
        }
        for (int i = 0; i < m; ++i) {
            const int   s = __shfl(s_l, i, 64);               // lane i: sub==i
            const float w = __shfl(w_l, (lane & 48) + i, 64); // same head group
            const float4 v = *(const float4*)(h + (size_t)s * NHD + col);
            acc.x += w * v.x;
            acc.y += w * v.y;
            acc.z += w * v.z;
            acc.w += w * v.w;
            dsum += w;
        }
    }

    const float inv = 1.0f / (dsum + 1e-16f);
    const float4 bb = *(const float4*)(bias + col);
    float4 o;
    o.x = fmaxf(acc.x * inv + bb.x, 0.f);
    o.y = fmaxf(acc.y * inv + bb.y, 0.f);
    o.z = fmaxf(acc.z * inv + bb.z, 0.f);
    o.w = fmaxf(acc.w * inv + bb.w, 0.f);
    *(float4*)(out + (size_t)node * NHD + col) = o;
}

// ------------------------------ pooling -------------------------------------
__global__ void graph_offsets_kernel(const int* __restrict__ batch, int* __restrict__ goff)
{
    const int n = blockIdx.x * 256 + threadIdx.x;
    if (n >= N_NODES) return;
    const int b  = batch[n];
    const int bp = (n == 0) ? -1 : batch[n - 1];
    for (int g = bp + 1; g <= b; ++g) goff[g] = n;
    if (n == N_NODES - 1) {
        for (int g = b + 1; g <= NGRAPH; ++g) goff[g] = N_NODES;
    }
}

#define PRB 128

__global__ __launch_bounds__(640) void pool_sum_kernel(
    const float* __restrict__ x, const float* __restrict__ h1,
    const float* __restrict__ h2, const int* __restrict__ batch,
    float* __restrict__ sums)
{
    __shared__ int bsh[PRB];
    const int c  = threadIdx.x;            // 0..639
    const int r0 = blockIdx.x * PRB;
    const int r1 = min(N_NODES, r0 + PRB);
    const int nr = r1 - r0;
    if (c < nr) bsh[c] = batch[r0 + c];
    __syncthreads();

    const float* src; int ld, cc;
    if (c < INCH)            { src = x;  ld = INCH; cc = c; }
    else if (c < INCH + NHD) { src = h1; ld = NHD;  cc = c - INCH; }
    else                     { src = h2; ld = NHD;  cc = c - INCH - NHD; }

    float sum = 0.f;
    int g = bsh[0];
    for (int i = 0; i < nr; ++i) {
        const int gb = bsh[i];
        if (gb != g) {
            atomicAdd(&sums[g * DCAT + c], sum);
            sum = 0.f;
            g = gb;
        }
        sum += src[(size_t)(r0 + i) * ld + cc];
    }
    atomicAdd(&sums[g * DCAT + c], sum);
}

__global__ void pool_finalize_kernel(const float* __restrict__ sums,
                                     const int* __restrict__ goff,
                                     float* __restrict__ pooled)
{
    const int i = blockIdx.x * 256 + threadIdx.x;
    if (i >= NGRAPH * DCAT) return;
    const int g = i / DCAT;
    const float cnt = (float)(goff[g + 1] - goff[g]);
    pooled[i] = sums[i] / fmaxf(cnt, 1.0f);
}

// ------------------------------ MLP head ------------------------------------
__global__ __launch_bounds__(256) void mlp_kernel(
    const float* __restrict__ pooled, const float* __restrict__ W3,
    const float* __restrict__ b3, const float* __restrict__ W4,
    const float* __restrict__ b4, float* __restrict__ out)
{
    const int g = blockIdx.x;
    __shared__ float p[DCAT];
    __shared__ float hm[256];
    for (int i = threadIdx.x; i < DCAT; i += 256) p[i] = pooled[(size_t)g * DCAT + i];
    __syncthreads();
    float s = b3[threadIdx.x];
    for (int k = 0; k < DCAT; ++k) s += p[k] * W3[(size_t)k * 256 + threadIdx.x];
    hm[threadIdx.x] = fmaxf(s, 0.f);
    __syncthreads();
    if (threadIdx.x < 128) {
        float o = b4[threadIdx.x];
        for (int k = 0; k < 256; ++k) o += hm[k] * W4[(size_t)k * 128 + threadIdx.x];
        out[(size_t)g * 128 + threadIdx.x] = o;
    }
}

// ------------------------------ launch --------------------------------------
extern "C" void kernel_launch(void* const* d_in, const int* in_sizes, int n_in,
                              void* d_out, int out_size, void* d_ws, size_t ws_size,
                              hipStream_t stream)
{
    const float* x     = (const float*)d_in[0];
    const int*   ei    = (const int*)d_in[1];
    const int*   batch = (const int*)d_in[2];
    const float* W1    = (const float*)d_in[3];
    const float* a1s   = (const float*)d_in[4];
    const float* a1d   = (const float*)d_in[5];
    const float* b1    = (const float*)d_in[6];
    const float* W2    = (const float*)d_in[7];
    const float* a2s   = (const float*)d_in[8];
    const float* a2d   = (const float*)d_in[9];
    const float* b2    = (const float*)d_in[10];
    const float* W3    = (const float*)d_in[11];
    const float* b3    = (const float*)d_in[12];
    const float* W4    = (const float*)d_in[13];
    const float* b4    = (const float*)d_in[14];
    float* out = (float*)d_out;

    // workspace carve
    size_t off = 0;
    auto carve = [&](size_t bytes) -> void* {
        void* p = (char*)d_ws + off;
        off = (off + bytes + 255) & ~(size_t)255;
        return p;
    };
    float* hraw   = (float*)carve((size_t)N_NODES * NHD * 4);
    float* h1     = (float*)carve((size_t)N_NODES * NHD * 4);
    float* h2     = (float*)carve((size_t)N_NODES * NHD * 4);
    float* es     = (float*)carve((size_t)N_NODES * HEADS * 4);
    float* ed     = (float*)carve((size_t)N_NODES * HEADS * 4);
    float* pooled = (float*)carve((size_t)NGRAPH * DCAT * 4);
    float* psums  = (float*)carve((size_t)NGRAPH * DCAT * 4);
    int*   counts  = (int*)carve((size_t)N_NODES * 4);
    int*   offsets = (int*)carve((size_t)(N_NODES + 1) * 4);
    int*   cursor  = (int*)carve((size_t)N_NODES * 4);
    int*   csr     = (int*)carve((size_t)E_EDGES * 4);
    int*   goff    = (int*)carve((size_t)(NGRAPH + 1) * 4);

    const int egrid = (E_EDGES + 255) / 256;
    const int ngrid = (N_NODES + 255) / 256;

    // ---- CSR build (shared by both layers) ----
    hipMemsetAsync(counts, 0, (size_t)N_NODES * 4, stream);
    hist_kernel<<<egrid, 256, 0, stream>>>(ei, counts);
    scan_kernel<<<1, SCAN_T, 0, stream>>>(counts, offsets, cursor);
    scatter_kernel<<<egrid, 256, 0, stream>>>(ei, cursor, csr);
    graph_offsets_kernel<<<ngrid, 256, 0, stream>>>(batch, goff);

    dim3 ggrid((N_NODES + BM - 1) / BM, NHD / BN);

    // ---- layer 1 ----
    gemm_f32<<<ggrid, 256, 0, stream>>>(x, W1, hraw, N_NODES, INCH, NHD);
    attn_coef<<<N_NODES, 256, 0, stream>>>(hraw, a1s, a1d, es, ed);
    aggregate_fused<<<(N_NODES + 3) / 4, 256, 0, stream>>>(hraw, ei, csr, offsets,
                                                           es, ed, b1, h1);
    // ---- layer 2 ----
    gemm_f32<<<ggrid, 256, 0, stream>>>(h1, W2, hraw, N_NODES, NHD, NHD);
    attn_coef<<<N_NODES, 256, 0, stream>>>(hraw, a2s, a2d, es, ed);
    aggregate_fused<<<(N_NODES + 3) / 4, 256, 0, stream>>>(hraw, ei, csr, offsets,
                                                           es, ed, b2, h2);

    // ---- pooling + MLP ----
    hipMemsetAsync(psums, 0, (size_t)NGRAPH * DCAT * 4, stream);
    pool_sum_kernel<<<(N_NODES + PRB - 1) / PRB, 640, 0, stream>>>(x, h1, h2, batch, psums);
    pool_finalize_kernel<<<(NGRAPH * DCAT + 255) / 256, 256, 0, stream>>>(psums, goff, pooled);
    mlp_kernel<<<NGRAPH, 256, 0, stream>>>(pooled, W3, b3, W4, b4, out);
}

// Round 5
// 765.975 us; speedup vs baseline: 1.1153x; 1.1153x over previous
//
#include <hip/hip_runtime.h>
#include <cstdint>
#include <cstddef>

#define N_NODES 50000
#define E_EDGES 800000
#define INCH 128
#define HID 64
#define HEADS 4
#define NHD 256      // HEADS*HID
#define NGRAPH 64
#define DCAT 640     // 128 + 256 + 256
#define NEG_SLOPE 0.2f

typedef __attribute__((ext_vector_type(8))) short bf16x8;
typedef __attribute__((ext_vector_type(4))) float f32x4;

// round-to-nearest-even fp32 -> bf16 bits
static __device__ inline unsigned short f2bf(float f) {
    unsigned int u = __float_as_uint(f);
    unsigned int r = (u + 0x7FFFu + ((u >> 16) & 1u)) >> 16;
    return (unsigned short)r;
}
static __device__ inline float bf2f(unsigned short b) {
    return __uint_as_float(((unsigned int)b) << 16);
}

// ------------- weight pre-split: W[K,256] fp32 -> Wt{hi,lo}[256,K] bf16 ------
__global__ void wsplit_kernel(const float* __restrict__ W,
                              unsigned short* __restrict__ Wthi,
                              unsigned short* __restrict__ Wtlo, int K)
{
    const int i = blockIdx.x * 256 + threadIdx.x;   // i = n*K + k
    if (i >= K * NHD) return;
    const int n = i / K, k = i - n * K;
    const float v = W[(size_t)k * NHD + n];
    const unsigned short hi = f2bf(v);
    Wthi[i] = hi;
    Wtlo[i] = f2bf(v - bf2f(hi));
}

// ---------------- MFMA GEMM: C[M,256] = A[M,K] @ B[K,256] --------------------
// A fp32 (split to bf16 hi/lo during LDS staging); B pre-split+transposed.
// Block 256 thr = 4 waves (2x2 of 64x64), tile 128x128, K-chunk 32.
// C = Ahi@Bhi + Ahi@Blo + Alo@Bhi  (fp32 acc; lo*lo dropped ~2^-18)
#define GK 32
#define LDAB 40   // LDS row stride in elements (80B: b128 reads <=2-way aliasing)

__global__ __launch_bounds__(256, 2) void gemm_mfma(
    const float* __restrict__ A,
    const unsigned short* __restrict__ Bthi,
    const unsigned short* __restrict__ Btlo,
    float* __restrict__ C, int M, int K)
{
    __shared__ unsigned short Ahi[128 * LDAB];
    __shared__ unsigned short Alo[128 * LDAB];
    __shared__ unsigned short Bhi[128 * LDAB];
    __shared__ unsigned short Blo[128 * LDAB];

    const int t    = threadIdx.x;
    const int row0 = blockIdx.x * 128;
    const int col0 = blockIdx.y * 128;
    const int wave = t >> 6, lane = t & 63;
    const int wr = (wave >> 1) * 64;
    const int wc = (wave & 1) * 64;
    const int m16 = lane & 15, quad = lane >> 4;

    f32x4 acc[4][4];
#pragma unroll
    for (int i = 0; i < 4; ++i)
#pragma unroll
        for (int j = 0; j < 4; ++j) acc[i][j] = (f32x4){0.f, 0.f, 0.f, 0.f};

    for (int k0 = 0; k0 < K; k0 += GK) {
        // ---- stage A: 128 rows x 32 fp32 -> hi/lo bf16 LDS ----
#pragma unroll
        for (int i = 0; i < 4; ++i) {
            const int seg = t + i * 256;       // 1024 float4 segments
            const int r = seg >> 3, p = seg & 7;
            const int grow = row0 + r;
            float4 v = make_float4(0.f, 0.f, 0.f, 0.f);
            if (grow < M) v = *(const float4*)(A + (size_t)grow * K + k0 + p * 4);
            ushort4 hv, lv;
            hv.x = f2bf(v.x); lv.x = f2bf(v.x - bf2f(hv.x));
            hv.y = f2bf(v.y); lv.y = f2bf(v.y - bf2f(hv.y));
            hv.z = f2bf(v.z); lv.z = f2bf(v.z - bf2f(hv.z));
            hv.w = f2bf(v.w); lv.w = f2bf(v.w - bf2f(hv.w));
            *(ushort4*)(&Ahi[r * LDAB + p * 4]) = hv;
            *(ushort4*)(&Alo[r * LDAB + p * 4]) = lv;
        }
        // ---- stage B: row-major bf16 copy from Bt[256,K] ----
#pragma unroll
        for (int i = 0; i < 2; ++i) {
            const int seg = t + i * 256;       // 512 16B segments
            const int r = seg >> 2, p = seg & 3;
            const size_t goff = (size_t)(col0 + r) * K + k0 + p * 8;
            *(int4*)(&Bhi[r * LDAB + p * 8]) = *(const int4*)(Bthi + goff);
            *(int4*)(&Blo[r * LDAB + p * 8]) = *(const int4*)(Btlo + goff);
        }
        __syncthreads();

        bf16x8 afh[4], afl[4], bfh[4], bfl[4];
#pragma unroll
        for (int i = 0; i < 4; ++i) {
            const int r = wr + i * 16 + m16;
            afh[i] = *(const bf16x8*)(&Ahi[r * LDAB + quad * 8]);
            afl[i] = *(const bf16x8*)(&Alo[r * LDAB + quad * 8]);
        }
#pragma unroll
        for (int j = 0; j < 4; ++j) {
            const int n = wc + j * 16 + m16;
            bfh[j] = *(const bf16x8*)(&Bhi[n * LDAB + quad * 8]);
            bfl[j] = *(const bf16x8*)(&Blo[n * LDAB + quad * 8]);
        }
#pragma unroll
        for (int i = 0; i < 4; ++i)
#pragma unroll
            for (int j = 0; j < 4; ++j) {
                acc[i][j] = __builtin_amdgcn_mfma_f32_16x16x32_bf16(afh[i], bfh[j], acc[i][j], 0, 0, 0);
                acc[i][j] = __builtin_amdgcn_mfma_f32_16x16x32_bf16(afh[i], bfl[j], acc[i][j], 0, 0, 0);
                acc[i][j] = __builtin_amdgcn_mfma_f32_16x16x32_bf16(afl[i], bfh[j], acc[i][j], 0, 0, 0);
            }
        __syncthreads();
    }

    // epilogue: C/D layout col=lane&15, row=quad*4+reg
#pragma unroll
    for (int i = 0; i < 4; ++i)
#pragma unroll
        for (int reg = 0; reg < 4; ++reg) {
            const int r = row0 + wr + i * 16 + quad * 4 + reg;
            if (r < M) {
#pragma unroll
                for (int j = 0; j < 4; ++j)
                    C[(size_t)r * NHD + col0 + wc + j * 16 + m16] = acc[i][j][reg];
            }
        }
}

// ------------- attention coefficients: es[n,h] = <h[n,h,:], a_src[h,:]> ------
__global__ __launch_bounds__(256) void attn_coef(
    const float* __restrict__ h, const float* __restrict__ asrc,
    const float* __restrict__ adst, float* __restrict__ es, float* __restrict__ ed)
{
    const int n = blockIdx.x;
    const int t = threadIdx.x;
    const float v = h[(size_t)n * NHD + t];
    float s1 = v * asrc[t];
    float s2 = v * adst[t];
#pragma unroll
    for (int off = 32; off; off >>= 1) {
        s1 += __shfl_down(s1, off, 64);
        s2 += __shfl_down(s2, off, 64);
    }
    if ((t & 63) == 0) {
        es[n * HEADS + (t >> 6)] = s1;
        ed[n * HEADS + (t >> 6)] = s2;
    }
}

// ------------------------------ CSR build -----------------------------------
__global__ void hist_kernel(const int* __restrict__ ei, int* __restrict__ counts)
{
    const int e = blockIdx.x * 256 + threadIdx.x;
    if (e >= E_EDGES) return;
    atomicAdd(&counts[ei[E_EDGES + e]], 1);
}

#define SCAN_T 1024
#define SCAN_C ((N_NODES + SCAN_T - 1) / SCAN_T)   // 49

__global__ __launch_bounds__(1024) void scan_kernel(const int* __restrict__ counts,
                                                    int* __restrict__ offsets,
                                                    int* __restrict__ cursor)
{
    __shared__ int part[SCAN_T];
    const int t  = threadIdx.x;
    const int lo = t * SCAN_C;
    const int hi = min(N_NODES, lo + SCAN_C);
    int local[SCAN_C];
    int sum = 0;
    for (int i = lo; i < hi; ++i) { local[i - lo] = sum; sum += counts[i]; }
    part[t] = sum;
    __syncthreads();
    for (int off = 1; off < SCAN_T; off <<= 1) {
        const int v = (t >= off) ? part[t - off] : 0;
        __syncthreads();
        part[t] += v;
        __syncthreads();
    }
    const int base = (t == 0) ? 0 : part[t - 1];
    for (int i = lo; i < hi; ++i) {
        const int v = base + local[i - lo];
        offsets[i] = v;
        cursor[i]  = v;
    }
    if (t == SCAN_T - 1) offsets[N_NODES] = part[SCAN_T - 1];
}

__global__ void scatter_kernel(const int* __restrict__ ei, int* __restrict__ cursor,
                               int* __restrict__ csr)
{
    const int e = blockIdx.x * 256 + threadIdx.x;
    if (e >= E_EDGES) return;
    const int d = ei[E_EDGES + e];
    const int pos = atomicAdd(&cursor[d], 1);
    csr[pos] = e;
}

// ------- fused softmax + aggregation: one wave per dst node ------------------
__global__ __launch_bounds__(256) void aggregate_fused(
    const float* __restrict__ h, const int* __restrict__ ei,
    const int* __restrict__ csr, const int* __restrict__ offsets,
    const float* __restrict__ es, const float* __restrict__ ed,
    const float* __restrict__ bias, float* __restrict__ out)
{
    const int wid  = threadIdx.x >> 6;
    const int lane = threadIdx.x & 63;
    const int node = blockIdx.x * 4 + wid;
    if (node >= N_NODES) return;
    const int head = lane >> 4;          // col = lane*4 -> head = col/64
    const int col  = lane * 4;
    const int sub  = lane & 15;          // edge slot within 16-edge chunk

    const float edc = ed[node * 4 + head];
    const int beg = offsets[node], end = offsets[node + 1];

    float4 acc = make_float4(0.f, 0.f, 0.f, 0.f);
    float dsum = 0.f;

    for (int base = beg; base < end; base += 16) {
        const int m = min(16, end - base);
        int s_l = 0; float w_l = 0.f;
        if (sub < m) {
            const int eid = csr[base + sub];
            s_l = ei[eid];
            float u = es[s_l * 4 + head] + edc;
            u = u > 0.f ? u : NEG_SLOPE * u;
            w_l = expf(u);
        }
        for (int i = 0; i < m; ++i) {
            const int   s = __shfl(s_l, i, 64);
            const float w = __shfl(w_l, (lane & 48) + i, 64);
            const float4 v = *(const float4*)(h + (size_t)s * NHD + col);
            acc.x += w * v.x;
            acc.y += w * v.y;
            acc.z += w * v.z;
            acc.w += w * v.w;
            dsum += w;
        }
    }

    const float inv = 1.0f / (dsum + 1e-16f);
    const float4 bb = *(const float4*)(bias + col);
    float4 o;
    o.x = fmaxf(acc.x * inv + bb.x, 0.f);
    o.y = fmaxf(acc.y * inv + bb.y, 0.f);
    o.z = fmaxf(acc.z * inv + bb.z, 0.f);
    o.w = fmaxf(acc.w * inv + bb.w, 0.f);
    *(float4*)(out + (size_t)node * NHD + col) = o;
}

// ------------------------------ pooling -------------------------------------
__global__ void graph_offsets_kernel(const int* __restrict__ batch, int* __restrict__ goff)
{
    const int n = blockIdx.x * 256 + threadIdx.x;
    if (n >= N_NODES) return;
    const int b  = batch[n];
    const int bp = (n == 0) ? -1 : batch[n - 1];
    for (int g = bp + 1; g <= b; ++g) goff[g] = n;
    if (n == N_NODES - 1) {
        for (int g = b + 1; g <= NGRAPH; ++g) goff[g] = N_NODES;
    }
}

#define PRB 128

__global__ __launch_bounds__(640) void pool_sum_kernel(
    const float* __restrict__ x, const float* __restrict__ h1,
    const float* __restrict__ h2, const int* __restrict__ batch,
    float* __restrict__ sums)
{
    __shared__ int bsh[PRB];
    const int c  = threadIdx.x;            // 0..639
    const int r0 = blockIdx.x * PRB;
    const int r1 = min(N_NODES, r0 + PRB);
    const int nr = r1 - r0;
    if (c < nr) bsh[c] = batch[r0 + c];
    __syncthreads();

    const float* src; int ld, cc;
    if (c < INCH)            { src = x;  ld = INCH; cc = c; }
    else if (c < INCH + NHD) { src = h1; ld = NHD;  cc = c - INCH; }
    else                     { src = h2; ld = NHD;  cc = c - INCH - NHD; }

    float sum = 0.f;
    int g = bsh[0];
    for (int i = 0; i < nr; ++i) {
        const int gb = bsh[i];
        if (gb != g) {
            atomicAdd(&sums[g * DCAT + c], sum);
            sum = 0.f;
            g = gb;
        }
        sum += src[(size_t)(r0 + i) * ld + cc];
    }
    atomicAdd(&sums[g * DCAT + c], sum);
}

__global__ void pool_finalize_kernel(const float* __restrict__ sums,
                                     const int* __restrict__ goff,
                                     float* __restrict__ pooled)
{
    const int i = blockIdx.x * 256 + threadIdx.x;
    if (i >= NGRAPH * DCAT) return;
    const int g = i / DCAT;
    const float cnt = (float)(goff[g + 1] - goff[g]);
    pooled[i] = sums[i] / fmaxf(cnt, 1.0f);
}

// ------------------------------ MLP head ------------------------------------
__global__ __launch_bounds__(256) void mlp_kernel(
    const float* __restrict__ pooled, const float* __restrict__ W3,
    const float* __restrict__ b3, const float* __restrict__ W4,
    const float* __restrict__ b4, float* __restrict__ out)
{
    const int g = blockIdx.x;
    __shared__ float p[DCAT];
    __shared__ float hm[256];
    for (int i = threadIdx.x; i < DCAT; i += 256) p[i] = pooled[(size_t)g * DCAT + i];
    __syncthreads();
    float s = b3[threadIdx.x];
    for (int k = 0; k < DCAT; ++k) s += p[k] * W3[(size_t)k * 256 + threadIdx.x];
    hm[threadIdx.x] = fmaxf(s, 0.f);
    __syncthreads();
    if (threadIdx.x < 128) {
        float o = b4[threadIdx.x];
        for (int k = 0; k < 256; ++k) o += hm[k] * W4[(size_t)k * 128 + threadIdx.x];
        out[(size_t)g * 128 + threadIdx.x] = o;
    }
}

// ------------------------------ launch --------------------------------------
extern "C" void kernel_launch(void* const* d_in, const int* in_sizes, int n_in,
                              void* d_out, int out_size, void* d_ws, size_t ws_size,
                              hipStream_t stream)
{
    const float* x     = (const float*)d_in[0];
    const int*   ei    = (const int*)d_in[1];
    const int*   batch = (const int*)d_in[2];
    const float* W1    = (const float*)d_in[3];
    const float* a1s   = (const float*)d_in[4];
    const float* a1d   = (const float*)d_in[5];
    const float* b1    = (const float*)d_in[6];
    const float* W2    = (const float*)d_in[7];
    const float* a2s   = (const float*)d_in[8];
    const float* a2d   = (const float*)d_in[9];
    const float* b2    = (const float*)d_in[10];
    const float* W3    = (const float*)d_in[11];
    const float* b3    = (const float*)d_in[12];
    const float* W4    = (const float*)d_in[13];
    const float* b4    = (const float*)d_in[14];
    float* out = (float*)d_out;

    // workspace carve
    size_t off = 0;
    auto carve = [&](size_t bytes) -> void* {
        void* p = (char*)d_ws + off;
        off = (off + bytes + 255) & ~(size_t)255;
        return p;
    };
    float* hraw   = (float*)carve((size_t)N_NODES * NHD * 4);
    float* h1     = (float*)carve((size_t)N_NODES * NHD * 4);
    float* h2     = (float*)carve((size_t)N_NODES * NHD * 4);
    float* es     = (float*)carve((size_t)N_NODES * HEADS * 4);
    float* ed     = (float*)carve((size_t)N_NODES * HEADS * 4);
    float* pooled = (float*)carve((size_t)NGRAPH * DCAT * 4);
    float* psums  = (float*)carve((size_t)NGRAPH * DCAT * 4);
    int*   counts  = (int*)carve((size_t)N_NODES * 4);
    int*   offsets = (int*)carve((size_t)(N_NODES + 1) * 4);
    int*   cursor  = (int*)carve((size_t)N_NODES * 4);
    int*   csr     = (int*)carve((size_t)E_EDGES * 4);
    int*   goff    = (int*)carve((size_t)(NGRAPH + 1) * 4);
    unsigned short* w1thi = (unsigned short*)carve((size_t)NHD * INCH * 2);
    unsigned short* w1tlo = (unsigned short*)carve((size_t)NHD * INCH * 2);
    unsigned short* w2thi = (unsigned short*)carve((size_t)NHD * NHD * 2);
    unsigned short* w2tlo = (unsigned short*)carve((size_t)NHD * NHD * 2);

    const int egrid = (E_EDGES + 255) / 256;
    const int ngrid = (N_NODES + 255) / 256;

    // ---- CSR build + weight split (independent of layer compute) ----
    hipMemsetAsync(counts, 0, (size_t)N_NODES * 4, stream);
    hist_kernel<<<egrid, 256, 0, stream>>>(ei, counts);
    scan_kernel<<<1, SCAN_T, 0, stream>>>(counts, offsets, cursor);
    scatter_kernel<<<egrid, 256, 0, stream>>>(ei, cursor, csr);
    graph_offsets_kernel<<<ngrid, 256, 0, stream>>>(batch, goff);
    wsplit_kernel<<<(INCH * NHD + 255) / 256, 256, 0, stream>>>(W1, w1thi, w1tlo, INCH);
    wsplit_kernel<<<(NHD * NHD + 255) / 256, 256, 0, stream>>>(W2, w2thi, w2tlo, NHD);

    dim3 ggrid((N_NODES + 127) / 128, NHD / 128);

    // ---- layer 1 ----
    gemm_mfma<<<ggrid, 256, 0, stream>>>(x, w1thi, w1tlo, hraw, N_NODES, INCH);
    attn_coef<<<N_NODES, 256, 0, stream>>>(hraw, a1s, a1d, es, ed);
    aggregate_fused<<<(N_NODES + 3) / 4, 256, 0, stream>>>(hraw, ei, csr, offsets,
                                                           es, ed, b1, h1);
    // ---- layer 2 ----
    gemm_mfma<<<ggrid, 256, 0, stream>>>(h1, w2thi, w2tlo, hraw, N_NODES, NHD);
    attn_coef<<<N_NODES, 256, 0, stream>>>(hraw, a2s, a2d, es, ed);
    aggregate_fused<<<(N_NODES + 3) / 4, 256, 0, stream>>>(hraw, ei, csr, offsets,
                                                           es, ed, b2, h2);

    // ---- pooling + MLP ----
    hipMemsetAsync(psums, 0, (size_t)NGRAPH * DCAT * 4, stream);
    pool_sum_kernel<<<(N_NODES + PRB - 1) / PRB, 640, 0, stream>>>(x, h1, h2, batch, psums);
    pool_finalize_kernel<<<(NGRAPH * DCAT + 255) / 256, 256, 0, stream>>>(psums, goff, pooled);
    mlp_kernel<<<NGRAPH, 256, 0, stream>>>(pooled, W3, b3, W4, b4, out);
}

// Round 6
// 680.325 us; speedup vs baseline: 1.2557x; 1.1259x over previous
//
#include <hip/hip_runtime.h>
#include <cstdint>
#include <cstddef>

#define N_NODES 50000
#define E_EDGES 800000
#define INCH 128
#define HID 64
#define HEADS 4
#define NHD 256      // HEADS*HID
#define NGRAPH 64
#define DCAT 640     // 128 + 256 + 256
#define NEG_SLOPE 0.2f

typedef __attribute__((ext_vector_type(8))) short bf16x8;
typedef __attribute__((ext_vector_type(4))) float f32x4;

// round-to-nearest-even fp32 -> bf16 bits
static __device__ inline unsigned short f2bf(float f) {
    unsigned int u = __float_as_uint(f);
    unsigned int r = (u + 0x7FFFu + ((u >> 16) & 1u)) >> 16;
    return (unsigned short)r;
}
static __device__ inline float bf2f(unsigned short b) {
    return __uint_as_float(((unsigned int)b) << 16);
}

// ------------- weight pre-split: W[K,256] fp32 -> Wt{hi,lo}[256,K] bf16 ------
__global__ void wsplit_kernel(const float* __restrict__ W,
                              unsigned short* __restrict__ Wthi,
                              unsigned short* __restrict__ Wtlo, int K)
{
    const int i = blockIdx.x * 256 + threadIdx.x;   // i = n*K + k
    if (i >= K * NHD) return;
    const int n = i / K, k = i - n * K;
    const float v = W[(size_t)k * NHD + n];
    const unsigned short hi = f2bf(v);
    Wthi[i] = hi;
    Wtlo[i] = f2bf(v - bf2f(hi));
}

// ---------------- MFMA GEMM: C[M,256] = A[M,K] @ B[K,256] --------------------
// A fp32 (split to bf16 hi/lo during LDS staging); B pre-split+transposed.
// Emits fp32 C (for attn_coef / next GEMM) and bf16 Cb (for the edge gather).
#define GK 32
#define LDAB 40   // LDS row stride in elements (80B: b128 reads <=2-way aliasing)

__global__ __launch_bounds__(256, 2) void gemm_mfma(
    const float* __restrict__ A,
    const unsigned short* __restrict__ Bthi,
    const unsigned short* __restrict__ Btlo,
    float* __restrict__ C, unsigned short* __restrict__ Cb, int M, int K)
{
    __shared__ unsigned short Ahi[128 * LDAB];
    __shared__ unsigned short Alo[128 * LDAB];
    __shared__ unsigned short Bhi[128 * LDAB];
    __shared__ unsigned short Blo[128 * LDAB];

    const int t    = threadIdx.x;
    const int row0 = blockIdx.x * 128;
    const int col0 = blockIdx.y * 128;
    const int wave = t >> 6, lane = t & 63;
    const int wr = (wave >> 1) * 64;
    const int wc = (wave & 1) * 64;
    const int m16 = lane & 15, quad = lane >> 4;

    f32x4 acc[4][4];
#pragma unroll
    for (int i = 0; i < 4; ++i)
#pragma unroll
        for (int j = 0; j < 4; ++j) acc[i][j] = (f32x4){0.f, 0.f, 0.f, 0.f};

    for (int k0 = 0; k0 < K; k0 += GK) {
        // ---- stage A: 128 rows x 32 fp32 -> hi/lo bf16 LDS ----
#pragma unroll
        for (int i = 0; i < 4; ++i) {
            const int seg = t + i * 256;       // 1024 float4 segments
            const int r = seg >> 3, p = seg & 7;
            const int grow = row0 + r;
            float4 v = make_float4(0.f, 0.f, 0.f, 0.f);
            if (grow < M) v = *(const float4*)(A + (size_t)grow * K + k0 + p * 4);
            ushort4 hv, lv;
            hv.x = f2bf(v.x); lv.x = f2bf(v.x - bf2f(hv.x));
            hv.y = f2bf(v.y); lv.y = f2bf(v.y - bf2f(hv.y));
            hv.z = f2bf(v.z); lv.z = f2bf(v.z - bf2f(hv.z));
            hv.w = f2bf(v.w); lv.w = f2bf(v.w - bf2f(hv.w));
            *(ushort4*)(&Ahi[r * LDAB + p * 4]) = hv;
            *(ushort4*)(&Alo[r * LDAB + p * 4]) = lv;
        }
        // ---- stage B: row-major bf16 copy from Bt[256,K] ----
#pragma unroll
        for (int i = 0; i < 2; ++i) {
            const int seg = t + i * 256;       // 512 16B segments
            const int r = seg >> 2, p = seg & 3;
            const size_t goff = (size_t)(col0 + r) * K + k0 + p * 8;
            *(int4*)(&Bhi[r * LDAB + p * 8]) = *(const int4*)(Bthi + goff);
            *(int4*)(&Blo[r * LDAB + p * 8]) = *(const int4*)(Btlo + goff);
        }
        __syncthreads();

        bf16x8 afh[4], afl[4], bfh[4], bfl[4];
#pragma unroll
        for (int i = 0; i < 4; ++i) {
            const int r = wr + i * 16 + m16;
            afh[i] = *(const bf16x8*)(&Ahi[r * LDAB + quad * 8]);
            afl[i] = *(const bf16x8*)(&Alo[r * LDAB + quad * 8]);
        }
#pragma unroll
        for (int j = 0; j < 4; ++j) {
            const int n = wc + j * 16 + m16;
            bfh[j] = *(const bf16x8*)(&Bhi[n * LDAB + quad * 8]);
            bfl[j] = *(const bf16x8*)(&Blo[n * LDAB + quad * 8]);
        }
#pragma unroll
        for (int i = 0; i < 4; ++i)
#pragma unroll
            for (int j = 0; j < 4; ++j) {
                acc[i][j] = __builtin_amdgcn_mfma_f32_16x16x32_bf16(afh[i], bfh[j], acc[i][j], 0, 0, 0);
                acc[i][j] = __builtin_amdgcn_mfma_f32_16x16x32_bf16(afh[i], bfl[j], acc[i][j], 0, 0, 0);
                acc[i][j] = __builtin_amdgcn_mfma_f32_16x16x32_bf16(afl[i], bfh[j], acc[i][j], 0, 0, 0);
            }
        __syncthreads();
    }

    // epilogue: C/D layout col=lane&15, row=quad*4+reg; dual fp32+bf16 store
#pragma unroll
    for (int i = 0; i < 4; ++i)
#pragma unroll
        for (int reg = 0; reg < 4; ++reg) {
            const int r = row0 + wr + i * 16 + quad * 4 + reg;
            if (r < M) {
#pragma unroll
                for (int j = 0; j < 4; ++j) {
                    const float val = acc[i][j][reg];
                    const size_t idx = (size_t)r * NHD + col0 + wc + j * 16 + m16;
                    C[idx]  = val;
                    Cb[idx] = f2bf(val);
                }
            }
        }
}

// ------------- attention coefficients: es[n,h] = <h[n,h,:], a_src[h,:]> ------
__global__ __launch_bounds__(256) void attn_coef(
    const float* __restrict__ h, const float* __restrict__ asrc,
    const float* __restrict__ adst, float* __restrict__ es, float* __restrict__ ed)
{
    const int n = blockIdx.x;
    const int t = threadIdx.x;
    const float v = h[(size_t)n * NHD + t];
    float s1 = v * asrc[t];
    float s2 = v * adst[t];
#pragma unroll
    for (int off = 32; off; off >>= 1) {
        s1 += __shfl_down(s1, off, 64);
        s2 += __shfl_down(s2, off, 64);
    }
    if ((t & 63) == 0) {
        es[n * HEADS + (t >> 6)] = s1;
        ed[n * HEADS + (t >> 6)] = s2;
    }
}

// ------------------------------ CSR build -----------------------------------
__global__ void hist_kernel(const int* __restrict__ ei, int* __restrict__ counts)
{
    const int e = blockIdx.x * 256 + threadIdx.x;
    if (e >= E_EDGES) return;
    atomicAdd(&counts[ei[E_EDGES + e]], 1);
}

#define SCAN_T 1024
#define SCAN_C ((N_NODES + SCAN_T - 1) / SCAN_T)   // 49

__global__ __launch_bounds__(1024) void scan_kernel(const int* __restrict__ counts,
                                                    int* __restrict__ offsets,
                                                    int* __restrict__ cursor)
{
    __shared__ int part[SCAN_T];
    const int t  = threadIdx.x;
    const int lo = t * SCAN_C;
    const int hi = min(N_NODES, lo + SCAN_C);
    int local[SCAN_C];
    int sum = 0;
    for (int i = lo; i < hi; ++i) { local[i - lo] = sum; sum += counts[i]; }
    part[t] = sum;
    __syncthreads();
    for (int off = 1; off < SCAN_T; off <<= 1) {
        const int v = (t >= off) ? part[t - off] : 0;
        __syncthreads();
        part[t] += v;
        __syncthreads();
    }
    const int base = (t == 0) ? 0 : part[t - 1];
    for (int i = lo; i < hi; ++i) {
        const int v = base + local[i - lo];
        offsets[i] = v;
        cursor[i]  = v;
    }
    if (t == SCAN_T - 1) offsets[N_NODES] = part[SCAN_T - 1];
}

__global__ void scatter_kernel(const int* __restrict__ ei, int* __restrict__ cursor,
                               int* __restrict__ csr)
{
    const int e = blockIdx.x * 256 + threadIdx.x;
    if (e >= E_EDGES) return;
    const int d = ei[E_EDGES + e];
    const int pos = atomicAdd(&cursor[d], 1);
    csr[pos] = e;
}

// ------- fused softmax + aggregation: one wave per dst node ------------------
// Gathers h rows in bf16 (512B/row, half the fp32 traffic). Writes fp32 out
// (next layer's GEMM input; skipped when null) + bf16 outb (pooling input).
__global__ __launch_bounds__(256) void aggregate_fused(
    const unsigned short* __restrict__ hb, const int* __restrict__ ei,
    const int* __restrict__ csr, const int* __restrict__ offsets,
    const float* __restrict__ es, const float* __restrict__ ed,
    const float* __restrict__ bias, float* __restrict__ out,
    unsigned short* __restrict__ outb)
{
    const int wid  = threadIdx.x >> 6;
    const int lane = threadIdx.x & 63;
    const int node = blockIdx.x * 4 + wid;
    if (node >= N_NODES) return;
    const int head = lane >> 4;          // col = lane*4 -> head = col/64
    const int col  = lane * 4;
    const int sub  = lane & 15;          // edge slot within 16-edge chunk

    const float edc = ed[node * 4 + head];
    const int beg = offsets[node], end = offsets[node + 1];

    float4 acc = make_float4(0.f, 0.f, 0.f, 0.f);
    float dsum = 0.f;

    for (int base = beg; base < end; base += 16) {
        const int m = min(16, end - base);
        int s_l = 0; float w_l = 0.f;
        if (sub < m) {
            const int eid = csr[base + sub];
            s_l = ei[eid];
            float u = es[s_l * 4 + head] + edc;
            u = u > 0.f ? u : NEG_SLOPE * u;
            w_l = expf(u);
        }
        for (int i = 0; i < m; ++i) {
            const int   s = __shfl(s_l, i, 64);
            const float w = __shfl(w_l, (lane & 48) + i, 64);
            const ushort4 v = *(const ushort4*)(hb + (size_t)s * NHD + col);
            acc.x += w * bf2f(v.x);
            acc.y += w * bf2f(v.y);
            acc.z += w * bf2f(v.z);
            acc.w += w * bf2f(v.w);
            dsum += w;
        }
    }

    const float inv = 1.0f / (dsum + 1e-16f);
    const float4 bb = *(const float4*)(bias + col);
    float4 o;
    o.x = fmaxf(acc.x * inv + bb.x, 0.f);
    o.y = fmaxf(acc.y * inv + bb.y, 0.f);
    o.z = fmaxf(acc.z * inv + bb.z, 0.f);
    o.w = fmaxf(acc.w * inv + bb.w, 0.f);
    if (out) *(float4*)(out + (size_t)node * NHD + col) = o;
    ushort4 ob;
    ob.x = f2bf(o.x); ob.y = f2bf(o.y); ob.z = f2bf(o.z); ob.w = f2bf(o.w);
    *(ushort4*)(outb + (size_t)node * NHD + col) = ob;
}

// ------------------------------ pooling -------------------------------------
__global__ void graph_offsets_kernel(const int* __restrict__ batch, int* __restrict__ goff)
{
    const int n = blockIdx.x * 256 + threadIdx.x;
    if (n >= N_NODES) return;
    const int b  = batch[n];
    const int bp = (n == 0) ? -1 : batch[n - 1];
    for (int g = bp + 1; g <= b; ++g) goff[g] = n;
    if (n == N_NODES - 1) {
        for (int g = b + 1; g <= NGRAPH; ++g) goff[g] = N_NODES;
    }
}

#define PRB 128

__global__ __launch_bounds__(640) void pool_sum_kernel(
    const float* __restrict__ x, const unsigned short* __restrict__ h1b,
    const unsigned short* __restrict__ h2b, const int* __restrict__ batch,
    float* __restrict__ sums)
{
    __shared__ int bsh[PRB];
    const int c  = threadIdx.x;            // 0..639
    const int r0 = blockIdx.x * PRB;
    const int r1 = min(N_NODES, r0 + PRB);
    const int nr = r1 - r0;
    if (c < nr) bsh[c] = batch[r0 + c];
    __syncthreads();

    const float* srcf = nullptr;
    const unsigned short* srcb = nullptr;
    int ld, cc;
    if (c < INCH)            { srcf = x;   ld = INCH; cc = c; }
    else if (c < INCH + NHD) { srcb = h1b; ld = NHD;  cc = c - INCH; }
    else                     { srcb = h2b; ld = NHD;  cc = c - INCH - NHD; }

    float sum = 0.f;
    int g = bsh[0];
    for (int i = 0; i < nr; ++i) {
        const int gb = bsh[i];
        if (gb != g) {
            atomicAdd(&sums[g * DCAT + c], sum);
            sum = 0.f;
            g = gb;
        }
        sum += srcf ? srcf[(size_t)(r0 + i) * ld + cc]
                    : bf2f(srcb[(size_t)(r0 + i) * ld + cc]);
    }
    atomicAdd(&sums[g * DCAT + c], sum);
}

__global__ void pool_finalize_kernel(const float* __restrict__ sums,
                                     const int* __restrict__ goff,
                                     float* __restrict__ pooled)
{
    const int i = blockIdx.x * 256 + threadIdx.x;
    if (i >= NGRAPH * DCAT) return;
    const int g = i / DCAT;
    const float cnt = (float)(goff[g + 1] - goff[g]);
    pooled[i] = sums[i] / fmaxf(cnt, 1.0f);
}

// ------------------------------ MLP head ------------------------------------
__global__ __launch_bounds__(256) void mlp_kernel(
    const float* __restrict__ pooled, const float* __restrict__ W3,
    const float* __restrict__ b3, const float* __restrict__ W4,
    const float* __restrict__ b4, float* __restrict__ out)
{
    const int g = blockIdx.x;
    __shared__ float p[DCAT];
    __shared__ float hm[256];
    for (int i = threadIdx.x; i < DCAT; i += 256) p[i] = pooled[(size_t)g * DCAT + i];
    __syncthreads();
    float s = b3[threadIdx.x];
    for (int k = 0; k < DCAT; ++k) s += p[k] * W3[(size_t)k * 256 + threadIdx.x];
    hm[threadIdx.x] = fmaxf(s, 0.f);
    __syncthreads();
    if (threadIdx.x < 128) {
        float o = b4[threadIdx.x];
        for (int k = 0; k < 256; ++k) o += hm[k] * W4[(size_t)k * 128 + threadIdx.x];
        out[(size_t)g * 128 + threadIdx.x] = o;
    }
}

// ------------------------------ launch --------------------------------------
extern "C" void kernel_launch(void* const* d_in, const int* in_sizes, int n_in,
                              void* d_out, int out_size, void* d_ws, size_t ws_size,
                              hipStream_t stream)
{
    const float* x     = (const float*)d_in[0];
    const int*   ei    = (const int*)d_in[1];
    const int*   batch = (const int*)d_in[2];
    const float* W1    = (const float*)d_in[3];
    const float* a1s   = (const float*)d_in[4];
    const float* a1d   = (const float*)d_in[5];
    const float* b1    = (const float*)d_in[6];
    const float* W2    = (const float*)d_in[7];
    const float* a2s   = (const float*)d_in[8];
    const float* a2d   = (const float*)d_in[9];
    const float* b2    = (const float*)d_in[10];
    const float* W3    = (const float*)d_in[11];
    const float* b3    = (const float*)d_in[12];
    const float* W4    = (const float*)d_in[13];
    const float* b4    = (const float*)d_in[14];
    float* out = (float*)d_out;

    // workspace carve
    size_t off = 0;
    auto carve = [&](size_t bytes) -> void* {
        void* p = (char*)d_ws + off;
        off = (off + bytes + 255) & ~(size_t)255;
        return p;
    };
    float*          hraw  = (float*)carve((size_t)N_NODES * NHD * 4);
    unsigned short* hrawb = (unsigned short*)carve((size_t)N_NODES * NHD * 2);
    float*          h1    = (float*)carve((size_t)N_NODES * NHD * 4);
    unsigned short* h1b   = (unsigned short*)carve((size_t)N_NODES * NHD * 2);
    unsigned short* h2b   = (unsigned short*)carve((size_t)N_NODES * NHD * 2);
    float* es     = (float*)carve((size_t)N_NODES * HEADS * 4);
    float* ed     = (float*)carve((size_t)N_NODES * HEADS * 4);
    float* pooled = (float*)carve((size_t)NGRAPH * DCAT * 4);
    float* psums  = (float*)carve((size_t)NGRAPH * DCAT * 4);
    int*   counts  = (int*)carve((size_t)N_NODES * 4);
    int*   offsets = (int*)carve((size_t)(N_NODES + 1) * 4);
    int*   cursor  = (int*)carve((size_t)N_NODES * 4);
    int*   csr     = (int*)carve((size_t)E_EDGES * 4);
    int*   goff    = (int*)carve((size_t)(NGRAPH + 1) * 4);
    unsigned short* w1thi = (unsigned short*)carve((size_t)NHD * INCH * 2);
    unsigned short* w1tlo = (unsigned short*)carve((size_t)NHD * INCH * 2);
    unsigned short* w2thi = (unsigned short*)carve((size_t)NHD * NHD * 2);
    unsigned short* w2tlo = (unsigned short*)carve((size_t)NHD * NHD * 2);

    const int egrid = (E_EDGES + 255) / 256;
    const int ngrid = (N_NODES + 255) / 256;

    // ---- CSR build + weight split (independent of layer compute) ----
    hipMemsetAsync(counts, 0, (size_t)N_NODES * 4, stream);
    hist_kernel<<<egrid, 256, 0, stream>>>(ei, counts);
    scan_kernel<<<1, SCAN_T, 0, stream>>>(counts, offsets, cursor);
    scatter_kernel<<<egrid, 256, 0, stream>>>(ei, cursor, csr);
    graph_offsets_kernel<<<ngrid, 256, 0, stream>>>(batch, goff);
    wsplit_kernel<<<(INCH * NHD + 255) / 256, 256, 0, stream>>>(W1, w1thi, w1tlo, INCH);
    wsplit_kernel<<<(NHD * NHD + 255) / 256, 256, 0, stream>>>(W2, w2thi, w2tlo, NHD);

    dim3 ggrid((N_NODES + 127) / 128, NHD / 128);

    // ---- layer 1 ----
    gemm_mfma<<<ggrid, 256, 0, stream>>>(x, w1thi, w1tlo, hraw, hrawb, N_NODES, INCH);
    attn_coef<<<N_NODES, 256, 0, stream>>>(hraw, a1s, a1d, es, ed);
    aggregate_fused<<<(N_NODES + 3) / 4, 256, 0, stream>>>(hrawb, ei, csr, offsets,
                                                           es, ed, b1, h1, h1b);
    // ---- layer 2 ----
    gemm_mfma<<<ggrid, 256, 0, stream>>>(h1, w2thi, w2tlo, hraw, hrawb, N_NODES, NHD);
    attn_coef<<<N_NODES, 256, 0, stream>>>(hraw, a2s, a2d, es, ed);
    aggregate_fused<<<(N_NODES + 3) / 4, 256, 0, stream>>>(hrawb, ei, csr, offsets,
                                                           es, ed, b2, nullptr, h2b);

    // ---- pooling + MLP ----
    hipMemsetAsync(psums, 0, (size_t)NGRAPH * DCAT * 4, stream);
    pool_sum_kernel<<<(N_NODES + PRB - 1) / PRB, 640, 0, stream>>>(x, h1b, h2b, batch, psums);
    pool_finalize_kernel<<<(NGRAPH * DCAT + 255) / 256, 256, 0, stream>>>(psums, goff, pooled);
    mlp_kernel<<<NGRAPH, 256, 0, stream>>>(pooled, W3, b3, W4, b4, out);
}

// Round 7
// 584.994 us; speedup vs baseline: 1.4603x; 1.1630x over previous
//
#include <hip/hip_runtime.h>
#include <cstdint>
#include <cstddef>

#define N_NODES 50000
#define E_EDGES 800000
#define INCH 128
#define HID 64
#define HEADS 4
#define NHD 256      // HEADS*HID
#define NGRAPH 64
#define DCAT 640     // 128 + 256 + 256
#define NEG_SLOPE 0.2f

typedef __attribute__((ext_vector_type(8))) short bf16x8;
typedef __attribute__((ext_vector_type(4))) float f32x4;

// round-to-nearest-even fp32 -> bf16 bits
static __device__ inline unsigned short f2bf(float f) {
    unsigned int u = __float_as_uint(f);
    unsigned int r = (u + 0x7FFFu + ((u >> 16) & 1u)) >> 16;
    return (unsigned short)r;
}
static __device__ inline float bf2f(unsigned short b) {
    return __uint_as_float(((unsigned int)b) << 16);
}

// ------------- weight pre-split: W[K,256] fp32 -> Wt{hi,lo}[256,K] bf16 ------
__global__ void wsplit_kernel(const float* __restrict__ W,
                              unsigned short* __restrict__ Wthi,
                              unsigned short* __restrict__ Wtlo, int K)
{
    const int i = blockIdx.x * 256 + threadIdx.x;   // i = n*K + k
    if (i >= K * NHD) return;
    const int n = i / K, k = i - n * K;
    const float v = W[(size_t)k * NHD + n];
    const unsigned short hi = f2bf(v);
    Wthi[i] = hi;
    Wtlo[i] = f2bf(v - bf2f(hi));
}

// ---------------- MFMA GEMM: C[M,256] = A[M,K] @ B[K,256] --------------------
// A fp32 (split to bf16 hi/lo during LDS staging); B pre-split+transposed.
// Emits fp32 C (for attn_coef / next GEMM) and bf16 Cb (for the edge gather).
#define GK 32
#define LDAB 40   // LDS row stride in elements (80B: b128 reads <=2-way aliasing)

__global__ __launch_bounds__(256, 2) void gemm_mfma(
    const float* __restrict__ A,
    const unsigned short* __restrict__ Bthi,
    const unsigned short* __restrict__ Btlo,
    float* __restrict__ C, unsigned short* __restrict__ Cb, int M, int K)
{
    __shared__ unsigned short Ahi[128 * LDAB];
    __shared__ unsigned short Alo[128 * LDAB];
    __shared__ unsigned short Bhi[128 * LDAB];
    __shared__ unsigned short Blo[128 * LDAB];

    const int t    = threadIdx.x;
    const int row0 = blockIdx.x * 128;
    const int col0 = blockIdx.y * 128;
    const int wave = t >> 6, lane = t & 63;
    const int wr = (wave >> 1) * 64;
    const int wc = (wave & 1) * 64;
    const int m16 = lane & 15, quad = lane >> 4;

    f32x4 acc[4][4];
#pragma unroll
    for (int i = 0; i < 4; ++i)
#pragma unroll
        for (int j = 0; j < 4; ++j) acc[i][j] = (f32x4){0.f, 0.f, 0.f, 0.f};

    for (int k0 = 0; k0 < K; k0 += GK) {
        // ---- stage A: 128 rows x 32 fp32 -> hi/lo bf16 LDS ----
#pragma unroll
        for (int i = 0; i < 4; ++i) {
            const int seg = t + i * 256;       // 1024 float4 segments
            const int r = seg >> 3, p = seg & 7;
            const int grow = row0 + r;
            float4 v = make_float4(0.f, 0.f, 0.f, 0.f);
            if (grow < M) v = *(const float4*)(A + (size_t)grow * K + k0 + p * 4);
            ushort4 hv, lv;
            hv.x = f2bf(v.x); lv.x = f2bf(v.x - bf2f(hv.x));
            hv.y = f2bf(v.y); lv.y = f2bf(v.y - bf2f(hv.y));
            hv.z = f2bf(v.z); lv.z = f2bf(v.z - bf2f(hv.z));
            hv.w = f2bf(v.w); lv.w = f2bf(v.w - bf2f(hv.w));
            *(ushort4*)(&Ahi[r * LDAB + p * 4]) = hv;
            *(ushort4*)(&Alo[r * LDAB + p * 4]) = lv;
        }
        // ---- stage B: row-major bf16 copy from Bt[256,K] ----
#pragma unroll
        for (int i = 0; i < 2; ++i) {
            const int seg = t + i * 256;       // 512 16B segments
            const int r = seg >> 2, p = seg & 3;
            const size_t goff = (size_t)(col0 + r) * K + k0 + p * 8;
            *(int4*)(&Bhi[r * LDAB + p * 8]) = *(const int4*)(Bthi + goff);
            *(int4*)(&Blo[r * LDAB + p * 8]) = *(const int4*)(Btlo + goff);
        }
        __syncthreads();

        bf16x8 afh[4], afl[4], bfh[4], bfl[4];
#pragma unroll
        for (int i = 0; i < 4; ++i) {
            const int r = wr + i * 16 + m16;
            afh[i] = *(const bf16x8*)(&Ahi[r * LDAB + quad * 8]);
            afl[i] = *(const bf16x8*)(&Alo[r * LDAB + quad * 8]);
        }
#pragma unroll
        for (int j = 0; j < 4; ++j) {
            const int n = wc + j * 16 + m16;
            bfh[j] = *(const bf16x8*)(&Bhi[n * LDAB + quad * 8]);
            bfl[j] = *(const bf16x8*)(&Blo[n * LDAB + quad * 8]);
        }
#pragma unroll
        for (int i = 0; i < 4; ++i)
#pragma unroll
            for (int j = 0; j < 4; ++j) {
                acc[i][j] = __builtin_amdgcn_mfma_f32_16x16x32_bf16(afh[i], bfh[j], acc[i][j], 0, 0, 0);
                acc[i][j] = __builtin_amdgcn_mfma_f32_16x16x32_bf16(afh[i], bfl[j], acc[i][j], 0, 0, 0);
                acc[i][j] = __builtin_amdgcn_mfma_f32_16x16x32_bf16(afl[i], bfh[j], acc[i][j], 0, 0, 0);
            }
        __syncthreads();
    }

    // epilogue: C/D layout col=lane&15, row=quad*4+reg; dual fp32+bf16 store
#pragma unroll
    for (int i = 0; i < 4; ++i)
#pragma unroll
        for (int reg = 0; reg < 4; ++reg) {
            const int r = row0 + wr + i * 16 + quad * 4 + reg;
            if (r < M) {
#pragma unroll
                for (int j = 0; j < 4; ++j) {
                    const float val = acc[i][j][reg];
                    const size_t idx = (size_t)r * NHD + col0 + wc + j * 16 + m16;
                    C[idx]  = val;
                    Cb[idx] = f2bf(val);
                }
            }
        }
}

// ------------- attention coefficients: es[n,h] = <h[n,h,:], a_src[h,:]> ------
__global__ __launch_bounds__(256) void attn_coef(
    const float* __restrict__ h, const float* __restrict__ asrc,
    const float* __restrict__ adst, float* __restrict__ es, float* __restrict__ ed)
{
    const int n = blockIdx.x;
    const int t = threadIdx.x;
    const float v = h[(size_t)n * NHD + t];
    float s1 = v * asrc[t];
    float s2 = v * adst[t];
#pragma unroll
    for (int off = 32; off; off >>= 1) {
        s1 += __shfl_down(s1, off, 64);
        s2 += __shfl_down(s2, off, 64);
    }
    if ((t & 63) == 0) {
        es[n * HEADS + (t >> 6)] = s1;
        ed[n * HEADS + (t >> 6)] = s2;
    }
}

// ------------------------------ CSR build -----------------------------------
__global__ void hist_kernel(const int* __restrict__ ei, int* __restrict__ counts)
{
    const int e = blockIdx.x * 256 + threadIdx.x;
    if (e >= E_EDGES) return;
    atomicAdd(&counts[ei[E_EDGES + e]], 1);
}

// Multi-block scan: phase 1 = per-block LDS Hillis-Steele (parallel across
// 49 blocks), phase 2 = add block bases (49 adds by thread 0 of each block).
#define SBLK 1024
#define NSCB ((N_NODES + SBLK - 1) / SBLK)   // 49

__global__ __launch_bounds__(1024) void scan_local_kernel(
    const int* __restrict__ counts, int* __restrict__ offsets,
    int* __restrict__ bsum)
{
    __shared__ int tmp[SBLK];
    const int t = threadIdx.x;
    const int i = blockIdx.x * SBLK + t;
    const int v = (i < N_NODES) ? counts[i] : 0;
    tmp[t] = v;
    __syncthreads();
    for (int off = 1; off < SBLK; off <<= 1) {
        const int u = (t >= off) ? tmp[t - off] : 0;
        __syncthreads();
        tmp[t] += u;
        __syncthreads();
    }
    if (i < N_NODES) offsets[i] = tmp[t] - v;    // local exclusive prefix
    if (t == SBLK - 1) bsum[blockIdx.x] = tmp[t];
}

__global__ __launch_bounds__(1024) void scan_final_kernel(
    int* __restrict__ offsets, int* __restrict__ cursor,
    const int* __restrict__ bsum)
{
    __shared__ int base_sh;
    const int b = blockIdx.x;
    if (threadIdx.x == 0) {
        int s = 0;
        for (int j = 0; j < b; ++j) s += bsum[j];
        base_sh = s;
    }
    __syncthreads();
    const int i = b * SBLK + threadIdx.x;
    if (i < N_NODES) {
        const int v = offsets[i] + base_sh;
        offsets[i] = v;
        cursor[i]  = v;
    }
    if (b == 0 && threadIdx.x == 0) offsets[N_NODES] = E_EDGES;
}

__global__ void scatter_kernel(const int* __restrict__ ei, int* __restrict__ cursor,
                               int* __restrict__ csr)
{
    const int e = blockIdx.x * 256 + threadIdx.x;
    if (e >= E_EDGES) return;
    const int d = ei[E_EDGES + e];
    const int pos = atomicAdd(&cursor[d], 1);
    csr[pos] = e;
}

// ------- fused softmax + aggregation: one wave per dst node ------------------
// Gathers h rows in bf16 (512B/row). Writes fp32 out (next layer's GEMM
// input; skipped when null) + bf16 outb (pooling input).
__global__ __launch_bounds__(256) void aggregate_fused(
    const unsigned short* __restrict__ hb, const int* __restrict__ ei,
    const int* __restrict__ csr, const int* __restrict__ offsets,
    const float* __restrict__ es, const float* __restrict__ ed,
    const float* __restrict__ bias, float* __restrict__ out,
    unsigned short* __restrict__ outb)
{
    const int wid  = threadIdx.x >> 6;
    const int lane = threadIdx.x & 63;
    const int node = blockIdx.x * 4 + wid;
    if (node >= N_NODES) return;
    const int head = lane >> 4;          // col = lane*4 -> head = col/64
    const int col  = lane * 4;
    const int sub  = lane & 15;          // edge slot within 16-edge chunk

    const float edc = ed[node * 4 + head];
    const int beg = offsets[node], end = offsets[node + 1];

    float4 acc = make_float4(0.f, 0.f, 0.f, 0.f);
    float dsum = 0.f;

    for (int base = beg; base < end; base += 16) {
        const int m = min(16, end - base);
        int s_l = 0; float w_l = 0.f;
        if (sub < m) {
            const int eid = csr[base + sub];
            s_l = ei[eid];
            float u = es[s_l * 4 + head] + edc;
            u = u > 0.f ? u : NEG_SLOPE * u;
            w_l = expf(u);
        }
        for (int i = 0; i < m; ++i) {
            const int   s = __shfl(s_l, i, 64);
            const float w = __shfl(w_l, (lane & 48) + i, 64);
            const ushort4 v = *(const ushort4*)(hb + (size_t)s * NHD + col);
            acc.x += w * bf2f(v.x);
            acc.y += w * bf2f(v.y);
            acc.z += w * bf2f(v.z);
            acc.w += w * bf2f(v.w);
            dsum += w;
        }
    }

    const float inv = 1.0f / (dsum + 1e-16f);
    const float4 bb = *(const float4*)(bias + col);
    float4 o;
    o.x = fmaxf(acc.x * inv + bb.x, 0.f);
    o.y = fmaxf(acc.y * inv + bb.y, 0.f);
    o.z = fmaxf(acc.z * inv + bb.z, 0.f);
    o.w = fmaxf(acc.w * inv + bb.w, 0.f);
    if (out) *(float4*)(out + (size_t)node * NHD + col) = o;
    ushort4 ob;
    ob.x = f2bf(o.x); ob.y = f2bf(o.y); ob.z = f2bf(o.z); ob.w = f2bf(o.w);
    *(ushort4*)(outb + (size_t)node * NHD + col) = ob;
}

// ------------------------------ pooling -------------------------------------
__global__ void graph_offsets_kernel(const int* __restrict__ batch, int* __restrict__ goff)
{
    const int n = blockIdx.x * 256 + threadIdx.x;
    if (n >= N_NODES) return;
    const int b  = batch[n];
    const int bp = (n == 0) ? -1 : batch[n - 1];
    for (int g = bp + 1; g <= b; ++g) goff[g] = n;
    if (n == N_NODES - 1) {
        for (int g = b + 1; g <= NGRAPH; ++g) goff[g] = N_NODES;
    }
}

#define PRB 128

__global__ __launch_bounds__(640) void pool_sum_kernel(
    const float* __restrict__ x, const unsigned short* __restrict__ h1b,
    const unsigned short* __restrict__ h2b, const int* __restrict__ batch,
    float* __restrict__ sums)
{
    __shared__ int bsh[PRB];
    const int c  = threadIdx.x;            // 0..639
    const int r0 = blockIdx.x * PRB;
    const int r1 = min(N_NODES, r0 + PRB);
    const int nr = r1 - r0;
    if (c < nr) bsh[c] = batch[r0 + c];
    __syncthreads();

    const float* srcf = nullptr;
    const unsigned short* srcb = nullptr;
    int ld, cc;
    if (c < INCH)            { srcf = x;   ld = INCH; cc = c; }
    else if (c < INCH + NHD) { srcb = h1b; ld = NHD;  cc = c - INCH; }
    else                     { srcb = h2b; ld = NHD;  cc = c - INCH - NHD; }

    float sum = 0.f;
    int g = bsh[0];
    for (int i = 0; i < nr; ++i) {
        const int gb = bsh[i];
        if (gb != g) {
            atomicAdd(&sums[g * DCAT + c], sum);
            sum = 0.f;
            g = gb;
        }
        sum += srcf ? srcf[(size_t)(r0 + i) * ld + cc]
                    : bf2f(srcb[(size_t)(r0 + i) * ld + cc]);
    }
    atomicAdd(&sums[g * DCAT + c], sum);
}

__global__ void pool_finalize_kernel(const float* __restrict__ sums,
                                     const int* __restrict__ goff,
                                     float* __restrict__ pooled)
{
    const int i = blockIdx.x * 256 + threadIdx.x;
    if (i >= NGRAPH * DCAT) return;
    const int g = i / DCAT;
    const float cnt = (float)(goff[g + 1] - goff[g]);
    pooled[i] = sums[i] / fmaxf(cnt, 1.0f);
}

// ------------------------------ MLP head ------------------------------------
__global__ __launch_bounds__(256) void mlp_kernel(
    const float* __restrict__ pooled, const float* __restrict__ W3,
    const float* __restrict__ b3, const float* __restrict__ W4,
    const float* __restrict__ b4, float* __restrict__ out)
{
    const int g = blockIdx.x;
    __shared__ float p[DCAT];
    __shared__ float hm[256];
    for (int i = threadIdx.x; i < DCAT; i += 256) p[i] = pooled[(size_t)g * DCAT + i];
    __syncthreads();
    float s = b3[threadIdx.x];
    for (int k = 0; k < DCAT; ++k) s += p[k] * W3[(size_t)k * 256 + threadIdx.x];
    hm[threadIdx.x] = fmaxf(s, 0.f);
    __syncthreads();
    if (threadIdx.x < 128) {
        float o = b4[threadIdx.x];
        for (int k = 0; k < 256; ++k) o += hm[k] * W4[(size_t)k * 128 + threadIdx.x];
        out[(size_t)g * 128 + threadIdx.x] = o;
    }
}

// ------------------------------ launch --------------------------------------
extern "C" void kernel_launch(void* const* d_in, const int* in_sizes, int n_in,
                              void* d_out, int out_size, void* d_ws, size_t ws_size,
                              hipStream_t stream)
{
    const float* x     = (const float*)d_in[0];
    const int*   ei    = (const int*)d_in[1];
    const int*   batch = (const int*)d_in[2];
    const float* W1    = (const float*)d_in[3];
    const float* a1s   = (const float*)d_in[4];
    const float* a1d   = (const float*)d_in[5];
    const float* b1    = (const float*)d_in[6];
    const float* W2    = (const float*)d_in[7];
    const float* a2s   = (const float*)d_in[8];
    const float* a2d   = (const float*)d_in[9];
    const float* b2    = (const float*)d_in[10];
    const float* W3    = (const float*)d_in[11];
    const float* b3    = (const float*)d_in[12];
    const float* W4    = (const float*)d_in[13];
    const float* b4    = (const float*)d_in[14];
    float* out = (float*)d_out;

    // workspace carve
    size_t off = 0;
    auto carve = [&](size_t bytes) -> void* {
        void* p = (char*)d_ws + off;
        off = (off + bytes + 255) & ~(size_t)255;
        return p;
    };
    float*          hraw  = (float*)carve((size_t)N_NODES * NHD * 4);
    unsigned short* hrawb = (unsigned short*)carve((size_t)N_NODES * NHD * 2);
    float*          h1    = (float*)carve((size_t)N_NODES * NHD * 4);
    unsigned short* h1b   = (unsigned short*)carve((size_t)N_NODES * NHD * 2);
    unsigned short* h2b   = (unsigned short*)carve((size_t)N_NODES * NHD * 2);
    float* es     = (float*)carve((size_t)N_NODES * HEADS * 4);
    float* ed     = (float*)carve((size_t)N_NODES * HEADS * 4);
    float* pooled = (float*)carve((size_t)NGRAPH * DCAT * 4);
    float* psums  = (float*)carve((size_t)NGRAPH * DCAT * 4);
    int*   counts  = (int*)carve((size_t)N_NODES * 4);
    int*   offsets = (int*)carve((size_t)(N_NODES + 1) * 4);
    int*   cursor  = (int*)carve((size_t)N_NODES * 4);
    int*   csr     = (int*)carve((size_t)E_EDGES * 4);
    int*   goff    = (int*)carve((size_t)(NGRAPH + 1) * 4);
    int*   bsum    = (int*)carve((size_t)NSCB * 4);
    unsigned short* w1thi = (unsigned short*)carve((size_t)NHD * INCH * 2);
    unsigned short* w1tlo = (unsigned short*)carve((size_t)NHD * INCH * 2);
    unsigned short* w2thi = (unsigned short*)carve((size_t)NHD * NHD * 2);
    unsigned short* w2tlo = (unsigned short*)carve((size_t)NHD * NHD * 2);

    const int egrid = (E_EDGES + 255) / 256;
    const int ngrid = (N_NODES + 255) / 256;

    // ---- CSR build + weight split (independent of layer compute) ----
    hipMemsetAsync(counts, 0, (size_t)N_NODES * 4, stream);
    hist_kernel<<<egrid, 256, 0, stream>>>(ei, counts);
    scan_local_kernel<<<NSCB, SBLK, 0, stream>>>(counts, offsets, bsum);
    scan_final_kernel<<<NSCB, SBLK, 0, stream>>>(offsets, cursor, bsum);
    scatter_kernel<<<egrid, 256, 0, stream>>>(ei, cursor, csr);
    graph_offsets_kernel<<<ngrid, 256, 0, stream>>>(batch, goff);
    wsplit_kernel<<<(INCH * NHD + 255) / 256, 256, 0, stream>>>(W1, w1thi, w1tlo, INCH);
    wsplit_kernel<<<(NHD * NHD + 255) / 256, 256, 0, stream>>>(W2, w2thi, w2tlo, NHD);

    dim3 ggrid((N_NODES + 127) / 128, NHD / 128);

    // ---- layer 1 ----
    gemm_mfma<<<ggrid, 256, 0, stream>>>(x, w1thi, w1tlo, hraw, hrawb, N_NODES, INCH);
    attn_coef<<<N_NODES, 256, 0, stream>>>(hraw, a1s, a1d, es, ed);
    aggregate_fused<<<(N_NODES + 3) / 4, 256, 0, stream>>>(hrawb, ei, csr, offsets,
                                                           es, ed, b1, h1, h1b);
    // ---- layer 2 ----
    gemm_mfma<<<ggrid, 256, 0, stream>>>(h1, w2thi, w2tlo, hraw, hrawb, N_NODES, NHD);
    attn_coef<<<N_NODES, 256, 0, stream>>>(hraw, a2s, a2d, es, ed);
    aggregate_fused<<<(N_NODES + 3) / 4, 256, 0, stream>>>(hrawb, ei, csr, offsets,
                                                           es, ed, b2, nullptr, h2b);

    // ---- pooling + MLP ----
    hipMemsetAsync(psums, 0, (size_t)NGRAPH * DCAT * 4, stream);
    pool_sum_kernel<<<(N_NODES + PRB - 1) / PRB, 640, 0, stream>>>(x, h1b, h2b, batch, psums);
    pool_finalize_kernel<<<(NGRAPH * DCAT + 255) / 256, 256, 0, stream>>>(psums, goff, pooled);
    mlp_kernel<<<NGRAPH, 256, 0, stream>>>(pooled, W3, b3, W4, b4, out);
}

// Round 8
// 506.460 us; speedup vs baseline: 1.6867x; 1.1551x over previous
//
#include <hip/hip_runtime.h>
#include <cstdint>
#include <cstddef>

#define N_NODES 50000
#define E_EDGES 800000
#define INCH 128
#define HID 64
#define HEADS 4
#define NHD 256      // HEADS*HID
#define NGRAPH 64
#define DCAT 640     // 128 + 256 + 256
#define NEG_SLOPE 0.2f

typedef __attribute__((ext_vector_type(8))) short bf16x8;
typedef __attribute__((ext_vector_type(4))) float f32x4;

// round-to-nearest-even fp32 -> bf16 bits
static __device__ inline unsigned short f2bf(float f) {
    unsigned int u = __float_as_uint(f);
    unsigned int r = (u + 0x7FFFu + ((u >> 16) & 1u)) >> 16;
    return (unsigned short)r;
}
static __device__ inline float bf2f(unsigned short b) {
    return __uint_as_float(((unsigned int)b) << 16);
}

// ------------- weight pre-split: W[K,256] fp32 -> Wt{hi,lo}[256,K] bf16 ------
__global__ void wsplit_kernel(const float* __restrict__ W,
                              unsigned short* __restrict__ Wthi,
                              unsigned short* __restrict__ Wtlo, int K)
{
    const int i = blockIdx.x * 256 + threadIdx.x;   // i = n*K + k
    if (i >= K * NHD) return;
    const int n = i / K, k = i - n * K;
    const float v = W[(size_t)k * NHD + n];
    const unsigned short hi = f2bf(v);
    Wthi[i] = hi;
    Wtlo[i] = f2bf(v - bf2f(hi));
}

// ---------------- MFMA GEMM: Cb[M,256](bf16) = A[M,K] @ B[K,256] -------------
// A fp32 (split to bf16 hi/lo during LDS staging); B pre-split+transposed.
// Fused epilogue: es[n,h] = <C[n,h*64:...], asrc[h]>, ed likewise (each wave's
// 64x64 fragment covers exactly one head's columns; 4-step shfl_xor reduce
// over the 16 m16-lanes). The fp32 C is never written to memory.
#define GK 32
#define LDAB 40   // LDS row stride in elements (80B: b128 reads <=2-way aliasing)

__global__ __launch_bounds__(256, 2) void gemm_mfma(
    const float* __restrict__ A,
    const unsigned short* __restrict__ Bthi,
    const unsigned short* __restrict__ Btlo,
    const float* __restrict__ asrc, const float* __restrict__ adst,
    unsigned short* __restrict__ Cb, float* __restrict__ es,
    float* __restrict__ ed, int M, int K)
{
    __shared__ unsigned short Ahi[128 * LDAB];
    __shared__ unsigned short Alo[128 * LDAB];
    __shared__ unsigned short Bhi[128 * LDAB];
    __shared__ unsigned short Blo[128 * LDAB];

    const int t    = threadIdx.x;
    const int row0 = blockIdx.x * 128;
    const int col0 = blockIdx.y * 128;
    const int wave = t >> 6, lane = t & 63;
    const int wr = (wave >> 1) * 64;
    const int wc = (wave & 1) * 64;
    const int m16 = lane & 15, quad = lane >> 4;

    f32x4 acc[4][4];
#pragma unroll
    for (int i = 0; i < 4; ++i)
#pragma unroll
        for (int j = 0; j < 4; ++j) acc[i][j] = (f32x4){0.f, 0.f, 0.f, 0.f};

    for (int k0 = 0; k0 < K; k0 += GK) {
        // ---- stage A: 128 rows x 32 fp32 -> hi/lo bf16 LDS ----
#pragma unroll
        for (int i = 0; i < 4; ++i) {
            const int seg = t + i * 256;       // 1024 float4 segments
            const int r = seg >> 3, p = seg & 7;
            const int grow = row0 + r;
            float4 v = make_float4(0.f, 0.f, 0.f, 0.f);
            if (grow < M) v = *(const float4*)(A + (size_t)grow * K + k0 + p * 4);
            ushort4 hv, lv;
            hv.x = f2bf(v.x); lv.x = f2bf(v.x - bf2f(hv.x));
            hv.y = f2bf(v.y); lv.y = f2bf(v.y - bf2f(hv.y));
            hv.z = f2bf(v.z); lv.z = f2bf(v.z - bf2f(hv.z));
            hv.w = f2bf(v.w); lv.w = f2bf(v.w - bf2f(hv.w));
            *(ushort4*)(&Ahi[r * LDAB + p * 4]) = hv;
            *(ushort4*)(&Alo[r * LDAB + p * 4]) = lv;
        }
        // ---- stage B: row-major bf16 copy from Bt[256,K] ----
#pragma unroll
        for (int i = 0; i < 2; ++i) {
            const int seg = t + i * 256;       // 512 16B segments
            const int r = seg >> 2, p = seg & 3;
            const size_t goff = (size_t)(col0 + r) * K + k0 + p * 8;
            *(int4*)(&Bhi[r * LDAB + p * 8]) = *(const int4*)(Bthi + goff);
            *(int4*)(&Blo[r * LDAB + p * 8]) = *(const int4*)(Btlo + goff);
        }
        __syncthreads();

        bf16x8 afh[4], afl[4], bfh[4], bfl[4];
#pragma unroll
        for (int i = 0; i < 4; ++i) {
            const int r = wr + i * 16 + m16;
            afh[i] = *(const bf16x8*)(&Ahi[r * LDAB + quad * 8]);
            afl[i] = *(const bf16x8*)(&Alo[r * LDAB + quad * 8]);
        }
#pragma unroll
        for (int j = 0; j < 4; ++j) {
            const int n = wc + j * 16 + m16;
            bfh[j] = *(const bf16x8*)(&Bhi[n * LDAB + quad * 8]);
            bfl[j] = *(const bf16x8*)(&Blo[n * LDAB + quad * 8]);
        }
#pragma unroll
        for (int i = 0; i < 4; ++i)
#pragma unroll
            for (int j = 0; j < 4; ++j) {
                acc[i][j] = __builtin_amdgcn_mfma_f32_16x16x32_bf16(afh[i], bfh[j], acc[i][j], 0, 0, 0);
                acc[i][j] = __builtin_amdgcn_mfma_f32_16x16x32_bf16(afh[i], bfl[j], acc[i][j], 0, 0, 0);
                acc[i][j] = __builtin_amdgcn_mfma_f32_16x16x32_bf16(afl[i], bfh[j], acc[i][j], 0, 0, 0);
            }
        __syncthreads();
    }

    // ---- epilogue 1: bf16 C store (C/D layout col=lane&15, row=quad*4+reg)
#pragma unroll
    for (int i = 0; i < 4; ++i)
#pragma unroll
        for (int reg = 0; reg < 4; ++reg) {
            const int r = row0 + wr + i * 16 + quad * 4 + reg;
            if (r < M) {
#pragma unroll
                for (int j = 0; j < 4; ++j)
                    Cb[(size_t)r * NHD + col0 + wc + j * 16 + m16] = f2bf(acc[i][j][reg]);
            }
        }

    // ---- epilogue 2: fused attention coefficients for this wave's head ----
    const int head = (col0 + wc) >> 6;
    float a_s[4], a_d[4];
#pragma unroll
    for (int j = 0; j < 4; ++j) {
        a_s[j] = asrc[head * HID + j * 16 + m16];
        a_d[j] = adst[head * HID + j * 16 + m16];
    }
#pragma unroll
    for (int i = 0; i < 4; ++i)
#pragma unroll
        for (int reg = 0; reg < 4; ++reg) {
            float ps = 0.f, pd = 0.f;
#pragma unroll
            for (int j = 0; j < 4; ++j) {
                const float v = acc[i][j][reg];
                ps += v * a_s[j];
                pd += v * a_d[j];
            }
#pragma unroll
            for (int off = 1; off < 16; off <<= 1) {
                ps += __shfl_xor(ps, off, 64);
                pd += __shfl_xor(pd, off, 64);
            }
            if (m16 == 0) {
                const int r = row0 + wr + i * 16 + quad * 4 + reg;
                if (r < M) {
                    es[r * HEADS + head] = ps;
                    ed[r * HEADS + head] = pd;
                }
            }
        }
}

// ------------------------------ CSR build -----------------------------------
__global__ void hist_kernel(const int* __restrict__ ei, int* __restrict__ counts)
{
    const int e = blockIdx.x * 256 + threadIdx.x;
    if (e >= E_EDGES) return;
    atomicAdd(&counts[ei[E_EDGES + e]], 1);
}

#define SBLK 1024
#define NSCB ((N_NODES + SBLK - 1) / SBLK)   // 49

__global__ __launch_bounds__(1024) void scan_local_kernel(
    const int* __restrict__ counts, int* __restrict__ offsets,
    int* __restrict__ bsum)
{
    __shared__ int tmp[SBLK];
    const int t = threadIdx.x;
    const int i = blockIdx.x * SBLK + t;
    const int v = (i < N_NODES) ? counts[i] : 0;
    tmp[t] = v;
    __syncthreads();
    for (int off = 1; off < SBLK; off <<= 1) {
        const int u = (t >= off) ? tmp[t - off] : 0;
        __syncthreads();
        tmp[t] += u;
        __syncthreads();
    }
    if (i < N_NODES) offsets[i] = tmp[t] - v;    // local exclusive prefix
    if (t == SBLK - 1) bsum[blockIdx.x] = tmp[t];
}

__global__ __launch_bounds__(1024) void scan_final_kernel(
    int* __restrict__ offsets, int* __restrict__ cursor,
    const int* __restrict__ bsum)
{
    __shared__ int base_sh;
    const int b = blockIdx.x;
    if (threadIdx.x == 0) {
        int s = 0;
        for (int j = 0; j < b; ++j) s += bsum[j];
        base_sh = s;
    }
    __syncthreads();
    const int i = b * SBLK + threadIdx.x;
    if (i < N_NODES) {
        const int v = offsets[i] + base_sh;
        offsets[i] = v;
        cursor[i]  = v;
    }
    if (b == 0 && threadIdx.x == 0) offsets[N_NODES] = E_EDGES;
}

__global__ void scatter_kernel(const int* __restrict__ ei, int* __restrict__ cursor,
                               int* __restrict__ csr)
{
    const int e = blockIdx.x * 256 + threadIdx.x;
    if (e >= E_EDGES) return;
    const int d = ei[E_EDGES + e];
    const int pos = atomicAdd(&cursor[d], 1);
    csr[pos] = e;
}

// ------- fused softmax + aggregation: one wave per dst node ------------------
// v3: full 16-edge chunks run a fully-unrolled gather loop (16 loads in
// flight) with readlane-scalarized src row (SGPR base address). Next chunk's
// csr->ei->es chain is prefetched during the gathers.
__global__ __launch_bounds__(256) void aggregate_fused(
    const unsigned short* __restrict__ hb, const int* __restrict__ ei,
    const int* __restrict__ csr, const int* __restrict__ offsets,
    const float* __restrict__ es, const float* __restrict__ ed,
    const float* __restrict__ bias, float* __restrict__ out,
    unsigned short* __restrict__ outb)
{
    const int wid  = threadIdx.x >> 6;
    const int lane = threadIdx.x & 63;
    const int node = blockIdx.x * 4 + wid;
    if (node >= N_NODES) return;
    const int head = lane >> 4;          // col = lane*4 -> head = col/64
    const int col  = lane * 4;
    const int sub  = lane & 15;          // edge slot within 16-edge chunk

    const float edc = ed[node * 4 + head];
    const int beg = offsets[node], end = offsets[node + 1];

    float4 acc = make_float4(0.f, 0.f, 0.f, 0.f);
    float dsum = 0.f;

    int base = beg;
    int m_cur = min(16, end - base);
    int s_cur = 0; float w_cur = 0.f;
    if (base < end && sub < m_cur) {
        const int eid = csr[base + sub];
        s_cur = ei[eid];
        float u = es[s_cur * 4 + head] + edc;
        u = u > 0.f ? u : NEG_SLOPE * u;
        w_cur = expf(u);
    }

    while (base < end) {
        const int base_n = base + 16;
        const int m_nxt = min(16, end - base_n);
        int s_nxt = 0; float w_nxt = 0.f;
        if (base_n < end && sub < m_nxt) {
            const int eid = csr[base_n + sub];
            s_nxt = ei[eid];
            float u = es[s_nxt * 4 + head] + edc;
            u = u > 0.f ? u : NEG_SLOPE * u;
            w_nxt = expf(u);
        }
        if (m_cur == 16) {
#pragma unroll
            for (int i = 0; i < 16; ++i) {
                const int   s = (int)__builtin_amdgcn_readlane((unsigned)s_cur, i);
                const float w = __shfl(w_cur, (lane & 48) + i, 64);
                const ushort4 v = *(const ushort4*)(hb + (size_t)s * NHD + col);
                acc.x += w * bf2f(v.x);
                acc.y += w * bf2f(v.y);
                acc.z += w * bf2f(v.z);
                acc.w += w * bf2f(v.w);
                dsum += w;
            }
        } else {
            for (int i = 0; i < m_cur; ++i) {
                const int   s = __shfl(s_cur, i, 64);
                const float w = __shfl(w_cur, (lane & 48) + i, 64);
                const ushort4 v = *(const ushort4*)(hb + (size_t)s * NHD + col);
                acc.x += w * bf2f(v.x);
                acc.y += w * bf2f(v.y);
                acc.z += w * bf2f(v.z);
                acc.w += w * bf2f(v.w);
                dsum += w;
            }
        }
        s_cur = s_nxt; w_cur = w_nxt; m_cur = m_nxt; base = base_n;
    }

    const float inv = 1.0f / (dsum + 1e-16f);
    const float4 bb = *(const float4*)(bias + col);
    float4 o;
    o.x = fmaxf(acc.x * inv + bb.x, 0.f);
    o.y = fmaxf(acc.y * inv + bb.y, 0.f);
    o.z = fmaxf(acc.z * inv + bb.z, 0.f);
    o.w = fmaxf(acc.w * inv + bb.w, 0.f);
    if (out) *(float4*)(out + (size_t)node * NHD + col) = o;
    ushort4 ob;
    ob.x = f2bf(o.x); ob.y = f2bf(o.y); ob.z = f2bf(o.z); ob.w = f2bf(o.w);
    *(ushort4*)(outb + (size_t)node * NHD + col) = ob;
}

// ------------------------------ pooling -------------------------------------
__global__ void graph_offsets_kernel(const int* __restrict__ batch, int* __restrict__ goff)
{
    const int n = blockIdx.x * 256 + threadIdx.x;
    if (n >= N_NODES) return;
    const int b  = batch[n];
    const int bp = (n == 0) ? -1 : batch[n - 1];
    for (int g = bp + 1; g <= b; ++g) goff[g] = n;
    if (n == N_NODES - 1) {
        for (int g = b + 1; g <= NGRAPH; ++g) goff[g] = N_NODES;
    }
}

#define PRB 128

__global__ __launch_bounds__(640) void pool_sum_kernel(
    const float* __restrict__ x, const unsigned short* __restrict__ h1b,
    const unsigned short* __restrict__ h2b, const int* __restrict__ batch,
    float* __restrict__ sums)
{
    __shared__ int bsh[PRB];
    const int c  = threadIdx.x;            // 0..639
    const int r0 = blockIdx.x * PRB;
    const int r1 = min(N_NODES, r0 + PRB);
    const int nr = r1 - r0;
    if (c < nr) bsh[c] = batch[r0 + c];
    __syncthreads();

    const float* srcf = nullptr;
    const unsigned short* srcb = nullptr;
    int ld, cc;
    if (c < INCH)            { srcf = x;   ld = INCH; cc = c; }
    else if (c < INCH + NHD) { srcb = h1b; ld = NHD;  cc = c - INCH; }
    else                     { srcb = h2b; ld = NHD;  cc = c - INCH - NHD; }

    float sum = 0.f;
    int g = bsh[0];
    for (int i = 0; i < nr; ++i) {
        const int gb = bsh[i];
        if (gb != g) {
            atomicAdd(&sums[g * DCAT + c], sum);
            sum = 0.f;
            g = gb;
        }
        sum += srcf ? srcf[(size_t)(r0 + i) * ld + cc]
                    : bf2f(srcb[(size_t)(r0 + i) * ld + cc]);
    }
    atomicAdd(&sums[g * DCAT + c], sum);
}

__global__ void pool_finalize_kernel(const float* __restrict__ sums,
                                     const int* __restrict__ goff,
                                     float* __restrict__ pooled)
{
    const int i = blockIdx.x * 256 + threadIdx.x;
    if (i >= NGRAPH * DCAT) return;
    const int g = i / DCAT;
    const float cnt = (float)(goff[g + 1] - goff[g]);
    pooled[i] = sums[i] / fmaxf(cnt, 1.0f);
}

// ------------------------------ MLP head ------------------------------------
__global__ __launch_bounds__(256) void mlp_kernel(
    const float* __restrict__ pooled, const float* __restrict__ W3,
    const float* __restrict__ b3, const float* __restrict__ W4,
    const float* __restrict__ b4, float* __restrict__ out)
{
    const int g = blockIdx.x;
    __shared__ float p[DCAT];
    __shared__ float hm[256];
    for (int i = threadIdx.x; i < DCAT; i += 256) p[i] = pooled[(size_t)g * DCAT + i];
    __syncthreads();
    float s = b3[threadIdx.x];
    for (int k = 0; k < DCAT; ++k) s += p[k] * W3[(size_t)k * 256 + threadIdx.x];
    hm[threadIdx.x] = fmaxf(s, 0.f);
    __syncthreads();
    if (threadIdx.x < 128) {
        float o = b4[threadIdx.x];
        for (int k = 0; k < 256; ++k) o += hm[k] * W4[(size_t)k * 128 + threadIdx.x];
        out[(size_t)g * 128 + threadIdx.x] = o;
    }
}

// ------------------------------ launch --------------------------------------
extern "C" void kernel_launch(void* const* d_in, const int* in_sizes, int n_in,
                              void* d_out, int out_size, void* d_ws, size_t ws_size,
                              hipStream_t stream)
{
    const float* x     = (const float*)d_in[0];
    const int*   ei    = (const int*)d_in[1];
    const int*   batch = (const int*)d_in[2];
    const float* W1    = (const float*)d_in[3];
    const float* a1s   = (const float*)d_in[4];
    const float* a1d   = (const float*)d_in[5];
    const float* b1    = (const float*)d_in[6];
    const float* W2    = (const float*)d_in[7];
    const float* a2s   = (const float*)d_in[8];
    const float* a2d   = (const float*)d_in[9];
    const float* b2    = (const float*)d_in[10];
    const float* W3    = (const float*)d_in[11];
    const float* b3    = (const float*)d_in[12];
    const float* W4    = (const float*)d_in[13];
    const float* b4    = (const float*)d_in[14];
    float* out = (float*)d_out;

    // workspace carve
    size_t off = 0;
    auto carve = [&](size_t bytes) -> void* {
        void* p = (char*)d_ws + off;
        off = (off + bytes + 255) & ~(size_t)255;
        return p;
    };
    unsigned short* hrawb = (unsigned short*)carve((size_t)N_NODES * NHD * 2);
    float*          h1    = (float*)carve((size_t)N_NODES * NHD * 4);
    unsigned short* h1b   = (unsigned short*)carve((size_t)N_NODES * NHD * 2);
    unsigned short* h2b   = (unsigned short*)carve((size_t)N_NODES * NHD * 2);
    float* es     = (float*)carve((size_t)N_NODES * HEADS * 4);
    float* ed     = (float*)carve((size_t)N_NODES * HEADS * 4);
    float* pooled = (float*)carve((size_t)NGRAPH * DCAT * 4);
    float* psums  = (float*)carve((size_t)NGRAPH * DCAT * 4);
    int*   counts  = (int*)carve((size_t)N_NODES * 4);
    int*   offsets = (int*)carve((size_t)(N_NODES + 1) * 4);
    int*   cursor  = (int*)carve((size_t)N_NODES * 4);
    int*   csr     = (int*)carve((size_t)E_EDGES * 4);
    int*   goff    = (int*)carve((size_t)(NGRAPH + 1) * 4);
    int*   bsum    = (int*)carve((size_t)NSCB * 4);
    unsigned short* w1thi = (unsigned short*)carve((size_t)NHD * INCH * 2);
    unsigned short* w1tlo = (unsigned short*)carve((size_t)NHD * INCH * 2);
    unsigned short* w2thi = (unsigned short*)carve((size_t)NHD * NHD * 2);
    unsigned short* w2tlo = (unsigned short*)carve((size_t)NHD * NHD * 2);

    const int egrid = (E_EDGES + 255) / 256;
    const int ngrid = (N_NODES + 255) / 256;

    // ---- CSR build + weight split (independent of layer compute) ----
    hipMemsetAsync(counts, 0, (size_t)N_NODES * 4, stream);
    hist_kernel<<<egrid, 256, 0, stream>>>(ei, counts);
    scan_local_kernel<<<NSCB, SBLK, 0, stream>>>(counts, offsets, bsum);
    scan_final_kernel<<<NSCB, SBLK, 0, stream>>>(offsets, cursor, bsum);
    scatter_kernel<<<egrid, 256, 0, stream>>>(ei, cursor, csr);
    graph_offsets_kernel<<<ngrid, 256, 0, stream>>>(batch, goff);
    wsplit_kernel<<<(INCH * NHD + 255) / 256, 256, 0, stream>>>(W1, w1thi, w1tlo, INCH);
    wsplit_kernel<<<(NHD * NHD + 255) / 256, 256, 0, stream>>>(W2, w2thi, w2tlo, NHD);

    dim3 ggrid((N_NODES + 127) / 128, NHD / 128);

    // ---- layer 1 ----
    gemm_mfma<<<ggrid, 256, 0, stream>>>(x, w1thi, w1tlo, a1s, a1d,
                                         hrawb, es, ed, N_NODES, INCH);
    aggregate_fused<<<(N_NODES + 3) / 4, 256, 0, stream>>>(hrawb, ei, csr, offsets,
                                                           es, ed, b1, h1, h1b);
    // ---- layer 2 ----
    gemm_mfma<<<ggrid, 256, 0, stream>>>(h1, w2thi, w2tlo, a2s, a2d,
                                         hrawb, es, ed, N_NODES, NHD);
    aggregate_fused<<<(N_NODES + 3) / 4, 256, 0, stream>>>(hrawb, ei, csr, offsets,
                                                           es, ed, b2, nullptr, h2b);

    // ---- pooling + MLP ----
    hipMemsetAsync(psums, 0, (size_t)NGRAPH * DCAT * 4, stream);
    pool_sum_kernel<<<(N_NODES + PRB - 1) / PRB, 640, 0, stream>>>(x, h1b, h2b, batch, psums);
    pool_finalize_kernel<<<(NGRAPH * DCAT + 255) / 256, 256, 0, stream>>>(psums, goff, pooled);
    mlp_kernel<<<NGRAPH, 256, 0, stream>>>(pooled, W3, b3, W4, b4, out);
}

// Round 9
// 504.000 us; speedup vs baseline: 1.6950x; 1.0049x over previous
//
#include <hip/hip_runtime.h>
#include <cstdint>
#include <cstddef>

#define N_NODES 50000
#define M_PAD 50048    // 391 * 128, covers GEMM tile over-read
#define E_EDGES 800000
#define INCH 128
#define HID 64
#define HEADS 4
#define NHD 256      // HEADS*HID
#define NGRAPH 64
#define DCAT 640     // 128 + 256 + 256
#define NEG_SLOPE 0.2f

typedef __attribute__((ext_vector_type(8))) short bf16x8;
typedef __attribute__((ext_vector_type(4))) float f32x4;

// round-to-nearest-even fp32 -> bf16 bits
static __device__ inline unsigned short f2bf(float f) {
    unsigned int u = __float_as_uint(f);
    unsigned int r = (u + 0x7FFFu + ((u >> 16) & 1u)) >> 16;
    return (unsigned short)r;
}
static __device__ inline float bf2f(unsigned short b) {
    return __uint_as_float(((unsigned int)b) << 16);
}

// ------------- weight pre-split: W[K,256] fp32 -> Wt{hi,lo}[256,K] bf16 ------
__global__ void wsplit_kernel(const float* __restrict__ W,
                              unsigned short* __restrict__ Wthi,
                              unsigned short* __restrict__ Wtlo, int K)
{
    const int i = blockIdx.x * 256 + threadIdx.x;   // i = n*K + k
    if (i >= K * NHD) return;
    const int n = i / K, k = i - n * K;
    const float v = W[(size_t)k * NHD + n];
    const unsigned short hi = f2bf(v);
    Wthi[i] = hi;
    Wtlo[i] = f2bf(v - bf2f(hi));
}

// ------------- activation pre-split: A[n] fp32 -> hi/lo bf16 (flat) ----------
__global__ void asplit_kernel(const float* __restrict__ A,
                              unsigned short* __restrict__ Ahi,
                              unsigned short* __restrict__ Alo, int n)
{
    const int i = blockIdx.x * 256 + threadIdx.x;
    if (i >= n) return;
    const float v = A[i];
    const unsigned short h = f2bf(v);
    Ahi[i] = h;
    Alo[i] = f2bf(v - bf2f(h));
}

// ---------------- MFMA GEMM: Cb[M,256](bf16) = (Ahi+Alo) @ (Bhi+Blo) ---------
// All operands pre-split bf16: staging is pure 16B copies (no conversion VALU).
// Fused epilogue: es/ed per-head dots (wave's 64x64 fragment = one head).
#define GK 64
#define LDAB 72   // LDS row stride in elements (144B: b128 reads 2-way = free)

__global__ __launch_bounds__(256, 2) void gemm_mfma(
    const unsigned short* __restrict__ Athi,
    const unsigned short* __restrict__ Atlo,
    const unsigned short* __restrict__ Bthi,
    const unsigned short* __restrict__ Btlo,
    const float* __restrict__ asrc, const float* __restrict__ adst,
    unsigned short* __restrict__ Cb, float* __restrict__ es,
    float* __restrict__ ed, int M, int K)
{
    __shared__ unsigned short Ahi[128 * LDAB];
    __shared__ unsigned short Alo[128 * LDAB];
    __shared__ unsigned short Bhi[128 * LDAB];
    __shared__ unsigned short Blo[128 * LDAB];

    const int t    = threadIdx.x;
    const int row0 = blockIdx.x * 128;
    const int col0 = blockIdx.y * 128;
    const int wave = t >> 6, lane = t & 63;
    const int wr = (wave >> 1) * 64;
    const int wc = (wave & 1) * 64;
    const int m16 = lane & 15, quad = lane >> 4;

    f32x4 acc[4][4];
#pragma unroll
    for (int i = 0; i < 4; ++i)
#pragma unroll
        for (int j = 0; j < 4; ++j) acc[i][j] = (f32x4){0.f, 0.f, 0.f, 0.f};

    for (int k0 = 0; k0 < K; k0 += GK) {
        // ---- stage: A tile 128x64 + B tile 128x64, hi+lo, pure 16B copies ----
#pragma unroll
        for (int i = 0; i < 4; ++i) {
            const int seg = t + i * 256;       // 1024 segments of 8 bf16
            const int r = seg >> 3, p = (seg & 7) * 8;
            const size_t ga = (size_t)(row0 + r) * K + k0 + p;
            const size_t gb = (size_t)(col0 + r) * K + k0 + p;
            *(int4*)(&Ahi[r * LDAB + p]) = *(const int4*)(Athi + ga);
            *(int4*)(&Alo[r * LDAB + p]) = *(const int4*)(Atlo + ga);
            *(int4*)(&Bhi[r * LDAB + p]) = *(const int4*)(Bthi + gb);
            *(int4*)(&Blo[r * LDAB + p]) = *(const int4*)(Btlo + gb);
        }
        __syncthreads();

#pragma unroll
        for (int h = 0; h < 2; ++h) {
            bf16x8 afh[4], afl[4], bfh[4], bfl[4];
#pragma unroll
            for (int i = 0; i < 4; ++i) {
                const int r = wr + i * 16 + m16;
                afh[i] = *(const bf16x8*)(&Ahi[r * LDAB + h * 32 + quad * 8]);
                afl[i] = *(const bf16x8*)(&Alo[r * LDAB + h * 32 + quad * 8]);
            }
#pragma unroll
            for (int j = 0; j < 4; ++j) {
                const int n = wc + j * 16 + m16;
                bfh[j] = *(const bf16x8*)(&Bhi[n * LDAB + h * 32 + quad * 8]);
                bfl[j] = *(const bf16x8*)(&Blo[n * LDAB + h * 32 + quad * 8]);
            }
#pragma unroll
            for (int i = 0; i < 4; ++i)
#pragma unroll
                for (int j = 0; j < 4; ++j) {
                    acc[i][j] = __builtin_amdgcn_mfma_f32_16x16x32_bf16(afh[i], bfh[j], acc[i][j], 0, 0, 0);
                    acc[i][j] = __builtin_amdgcn_mfma_f32_16x16x32_bf16(afh[i], bfl[j], acc[i][j], 0, 0, 0);
                    acc[i][j] = __builtin_amdgcn_mfma_f32_16x16x32_bf16(afl[i], bfh[j], acc[i][j], 0, 0, 0);
                }
        }
        __syncthreads();
    }

    // ---- epilogue 1: bf16 C store (C/D layout col=lane&15, row=quad*4+reg)
#pragma unroll
    for (int i = 0; i < 4; ++i)
#pragma unroll
        for (int reg = 0; reg < 4; ++reg) {
            const int r = row0 + wr + i * 16 + quad * 4 + reg;
            if (r < M) {
#pragma unroll
                for (int j = 0; j < 4; ++j)
                    Cb[(size_t)r * NHD + col0 + wc + j * 16 + m16] = f2bf(acc[i][j][reg]);
            }
        }

    // ---- epilogue 2: fused attention coefficients for this wave's head ----
    const int head = (col0 + wc) >> 6;
    float a_s[4], a_d[4];
#pragma unroll
    for (int j = 0; j < 4; ++j) {
        a_s[j] = asrc[head * HID + j * 16 + m16];
        a_d[j] = adst[head * HID + j * 16 + m16];
    }
#pragma unroll
    for (int i = 0; i < 4; ++i)
#pragma unroll
        for (int reg = 0; reg < 4; ++reg) {
            float ps = 0.f, pd = 0.f;
#pragma unroll
            for (int j = 0; j < 4; ++j) {
                const float v = acc[i][j][reg];
                ps += v * a_s[j];
                pd += v * a_d[j];
            }
#pragma unroll
            for (int off = 1; off < 16; off <<= 1) {
                ps += __shfl_xor(ps, off, 64);
                pd += __shfl_xor(pd, off, 64);
            }
            if (m16 == 0) {
                const int r = row0 + wr + i * 16 + quad * 4 + reg;
                if (r < M) {
                    es[r * HEADS + head] = ps;
                    ed[r * HEADS + head] = pd;
                }
            }
        }
}

// ------------------------------ CSR build -----------------------------------
__global__ void hist_kernel(const int* __restrict__ ei, int* __restrict__ counts)
{
    const int e = blockIdx.x * 256 + threadIdx.x;
    if (e >= E_EDGES) return;
    atomicAdd(&counts[ei[E_EDGES + e]], 1);
}

#define SBLK 1024
#define NSCB ((N_NODES + SBLK - 1) / SBLK)   // 49

__global__ __launch_bounds__(1024) void scan_local_kernel(
    const int* __restrict__ counts, int* __restrict__ offsets,
    int* __restrict__ bsum)
{
    __shared__ int tmp[SBLK];
    const int t = threadIdx.x;
    const int i = blockIdx.x * SBLK + t;
    const int v = (i < N_NODES) ? counts[i] : 0;
    tmp[t] = v;
    __syncthreads();
    for (int off = 1; off < SBLK; off <<= 1) {
        const int u = (t >= off) ? tmp[t - off] : 0;
        __syncthreads();
        tmp[t] += u;
        __syncthreads();
    }
    if (i < N_NODES) offsets[i] = tmp[t] - v;    // local exclusive prefix
    if (t == SBLK - 1) bsum[blockIdx.x] = tmp[t];
}

__global__ __launch_bounds__(1024) void scan_final_kernel(
    int* __restrict__ offsets, int* __restrict__ cursor,
    const int* __restrict__ bsum)
{
    __shared__ int base_sh;
    const int b = blockIdx.x;
    if (threadIdx.x == 0) {
        int s = 0;
        for (int j = 0; j < b; ++j) s += bsum[j];
        base_sh = s;
    }
    __syncthreads();
    const int i = b * SBLK + threadIdx.x;
    if (i < N_NODES) {
        const int v = offsets[i] + base_sh;
        offsets[i] = v;
        cursor[i]  = v;
    }
    if (b == 0 && threadIdx.x == 0) offsets[N_NODES] = E_EDGES;
}

__global__ void scatter_kernel(const int* __restrict__ ei, int* __restrict__ cursor,
                               int* __restrict__ csr)
{
    const int e = blockIdx.x * 256 + threadIdx.x;
    if (e >= E_EDGES) return;
    const int d = ei[E_EDGES + e];
    const int pos = atomicAdd(&cursor[d], 1);
    csr[pos] = e;
}

// ------- fused softmax + aggregation: one wave per dst node ------------------
// Gathers bf16 h rows; writes hi bf16 output always, lo bf16 output when the
// next layer's GEMM needs the full-precision (hi+lo) activation.
__global__ __launch_bounds__(256) void aggregate_fused(
    const unsigned short* __restrict__ hb, const int* __restrict__ ei,
    const int* __restrict__ csr, const int* __restrict__ offsets,
    const float* __restrict__ es, const float* __restrict__ ed,
    const float* __restrict__ bias, unsigned short* __restrict__ outhi,
    unsigned short* __restrict__ outlo)
{
    const int wid  = threadIdx.x >> 6;
    const int lane = threadIdx.x & 63;
    const int node = blockIdx.x * 4 + wid;
    if (node >= N_NODES) return;
    const int head = lane >> 4;          // col = lane*4 -> head = col/64
    const int col  = lane * 4;
    const int sub  = lane & 15;          // edge slot within 16-edge chunk

    const float edc = ed[node * 4 + head];
    const int beg = offsets[node], end = offsets[node + 1];

    float4 acc = make_float4(0.f, 0.f, 0.f, 0.f);
    float dsum = 0.f;

    int base = beg;
    int m_cur = min(16, end - base);
    int s_cur = 0; float w_cur = 0.f;
    if (base < end && sub < m_cur) {
        const int eid = csr[base + sub];
        s_cur = ei[eid];
        float u = es[s_cur * 4 + head] + edc;
        u = u > 0.f ? u : NEG_SLOPE * u;
        w_cur = expf(u);
    }

    while (base < end) {
        const int base_n = base + 16;
        const int m_nxt = min(16, end - base_n);
        int s_nxt = 0; float w_nxt = 0.f;
        if (base_n < end && sub < m_nxt) {
            const int eid = csr[base_n + sub];
            s_nxt = ei[eid];
            float u = es[s_nxt * 4 + head] + edc;
            u = u > 0.f ? u : NEG_SLOPE * u;
            w_nxt = expf(u);
        }
        if (m_cur == 16) {
#pragma unroll
            for (int i = 0; i < 16; ++i) {
                const int   s = (int)__builtin_amdgcn_readlane((unsigned)s_cur, i);
                const float w = __shfl(w_cur, (lane & 48) + i, 64);
                const ushort4 v = *(const ushort4*)(hb + (size_t)s * NHD + col);
                acc.x += w * bf2f(v.x);
                acc.y += w * bf2f(v.y);
                acc.z += w * bf2f(v.z);
                acc.w += w * bf2f(v.w);
                dsum += w;
            }
        } else {
            for (int i = 0; i < m_cur; ++i) {
                const int   s = __shfl(s_cur, i, 64);
                const float w = __shfl(w_cur, (lane & 48) + i, 64);
                const ushort4 v = *(const ushort4*)(hb + (size_t)s * NHD + col);
                acc.x += w * bf2f(v.x);
                acc.y += w * bf2f(v.y);
                acc.z += w * bf2f(v.z);
                acc.w += w * bf2f(v.w);
                dsum += w;
            }
        }
        s_cur = s_nxt; w_cur = w_nxt; m_cur = m_nxt; base = base_n;
    }

    const float inv = 1.0f / (dsum + 1e-16f);
    const float4 bb = *(const float4*)(bias + col);
    float4 o;
    o.x = fmaxf(acc.x * inv + bb.x, 0.f);
    o.y = fmaxf(acc.y * inv + bb.y, 0.f);
    o.z = fmaxf(acc.z * inv + bb.z, 0.f);
    o.w = fmaxf(acc.w * inv + bb.w, 0.f);
    ushort4 oh;
    oh.x = f2bf(o.x); oh.y = f2bf(o.y); oh.z = f2bf(o.z); oh.w = f2bf(o.w);
    *(ushort4*)(outhi + (size_t)node * NHD + col) = oh;
    if (outlo) {
        ushort4 ol;
        ol.x = f2bf(o.x - bf2f(oh.x));
        ol.y = f2bf(o.y - bf2f(oh.y));
        ol.z = f2bf(o.z - bf2f(oh.z));
        ol.w = f2bf(o.w - bf2f(oh.w));
        *(ushort4*)(outlo + (size_t)node * NHD + col) = ol;
    }
}

// ------------------------------ pooling -------------------------------------
__global__ void graph_offsets_kernel(const int* __restrict__ batch, int* __restrict__ goff)
{
    const int n = blockIdx.x * 256 + threadIdx.x;
    if (n >= N_NODES) return;
    const int b  = batch[n];
    const int bp = (n == 0) ? -1 : batch[n - 1];
    for (int g = bp + 1; g <= b; ++g) goff[g] = n;
    if (n == N_NODES - 1) {
        for (int g = b + 1; g <= NGRAPH; ++g) goff[g] = N_NODES;
    }
}

#define PRB 128

__global__ __launch_bounds__(640) void pool_sum_kernel(
    const float* __restrict__ x, const unsigned short* __restrict__ h1b,
    const unsigned short* __restrict__ h2b, const int* __restrict__ batch,
    float* __restrict__ sums)
{
    __shared__ int bsh[PRB];
    const int c  = threadIdx.x;            // 0..639
    const int r0 = blockIdx.x * PRB;
    const int r1 = min(N_NODES, r0 + PRB);
    const int nr = r1 - r0;
    if (c < nr) bsh[c] = batch[r0 + c];
    __syncthreads();

    const float* srcf = nullptr;
    const unsigned short* srcb = nullptr;
    int ld, cc;
    if (c < INCH)            { srcf = x;   ld = INCH; cc = c; }
    else if (c < INCH + NHD) { srcb = h1b; ld = NHD;  cc = c - INCH; }
    else                     { srcb = h2b; ld = NHD;  cc = c - INCH - NHD; }

    float sum = 0.f;
    int g = bsh[0];
    for (int i = 0; i < nr; ++i) {
        const int gb = bsh[i];
        if (gb != g) {
            atomicAdd(&sums[g * DCAT + c], sum);
            sum = 0.f;
            g = gb;
        }
        sum += srcf ? srcf[(size_t)(r0 + i) * ld + cc]
                    : bf2f(srcb[(size_t)(r0 + i) * ld + cc]);
    }
    atomicAdd(&sums[g * DCAT + c], sum);
}

__global__ void pool_finalize_kernel(const float* __restrict__ sums,
                                     const int* __restrict__ goff,
                                     float* __restrict__ pooled)
{
    const int i = blockIdx.x * 256 + threadIdx.x;
    if (i >= NGRAPH * DCAT) return;
    const int g = i / DCAT;
    const float cnt = (float)(goff[g + 1] - goff[g]);
    pooled[i] = sums[i] / fmaxf(cnt, 1.0f);
}

// ------------------------------ MLP head ------------------------------------
__global__ __launch_bounds__(256) void mlp_kernel(
    const float* __restrict__ pooled, const float* __restrict__ W3,
    const float* __restrict__ b3, const float* __restrict__ W4,
    const float* __restrict__ b4, float* __restrict__ out)
{
    const int g = blockIdx.x;
    __shared__ float p[DCAT];
    __shared__ float hm[256];
    for (int i = threadIdx.x; i < DCAT; i += 256) p[i] = pooled[(size_t)g * DCAT + i];
    __syncthreads();
    float s = b3[threadIdx.x];
    for (int k = 0; k < DCAT; ++k) s += p[k] * W3[(size_t)k * 256 + threadIdx.x];
    hm[threadIdx.x] = fmaxf(s, 0.f);
    __syncthreads();
    if (threadIdx.x < 128) {
        float o = b4[threadIdx.x];
        for (int k = 0; k < 256; ++k) o += hm[k] * W4[(size_t)k * 128 + threadIdx.x];
        out[(size_t)g * 128 + threadIdx.x] = o;
    }
}

// ------------------------------ launch --------------------------------------
extern "C" void kernel_launch(void* const* d_in, const int* in_sizes, int n_in,
                              void* d_out, int out_size, void* d_ws, size_t ws_size,
                              hipStream_t stream)
{
    const float* x     = (const float*)d_in[0];
    const int*   ei    = (const int*)d_in[1];
    const int*   batch = (const int*)d_in[2];
    const float* W1    = (const float*)d_in[3];
    const float* a1s   = (const float*)d_in[4];
    const float* a1d   = (const float*)d_in[5];
    const float* b1    = (const float*)d_in[6];
    const float* W2    = (const float*)d_in[7];
    const float* a2s   = (const float*)d_in[8];
    const float* a2d   = (const float*)d_in[9];
    const float* b2    = (const float*)d_in[10];
    const float* W3    = (const float*)d_in[11];
    const float* b3    = (const float*)d_in[12];
    const float* W4    = (const float*)d_in[13];
    const float* b4    = (const float*)d_in[14];
    float* out = (float*)d_out;

    // workspace carve
    size_t off = 0;
    auto carve = [&](size_t bytes) -> void* {
        void* p = (char*)d_ws + off;
        off = (off + bytes + 255) & ~(size_t)255;
        return p;
    };
    unsigned short* xhi   = (unsigned short*)carve((size_t)M_PAD * INCH * 2);
    unsigned short* xlo   = (unsigned short*)carve((size_t)M_PAD * INCH * 2);
    unsigned short* ghi   = (unsigned short*)carve((size_t)N_NODES * NHD * 2);  // GEMM out (gather src)
    unsigned short* h1hi  = (unsigned short*)carve((size_t)M_PAD * NHD * 2);
    unsigned short* h1lo  = (unsigned short*)carve((size_t)M_PAD * NHD * 2);
    unsigned short* h2hi  = (unsigned short*)carve((size_t)N_NODES * NHD * 2);
    float* es     = (float*)carve((size_t)N_NODES * HEADS * 4);
    float* ed     = (float*)carve((size_t)N_NODES * HEADS * 4);
    float* pooled = (float*)carve((size_t)NGRAPH * DCAT * 4);
    float* psums  = (float*)carve((size_t)NGRAPH * DCAT * 4);
    int*   counts  = (int*)carve((size_t)N_NODES * 4);
    int*   offsets = (int*)carve((size_t)(N_NODES + 1) * 4);
    int*   cursor  = (int*)carve((size_t)N_NODES * 4);
    int*   csr     = (int*)carve((size_t)E_EDGES * 4);
    int*   goff    = (int*)carve((size_t)(NGRAPH + 1) * 4);
    int*   bsum    = (int*)carve((size_t)NSCB * 4);
    unsigned short* w1thi = (unsigned short*)carve((size_t)NHD * INCH * 2);
    unsigned short* w1tlo = (unsigned short*)carve((size_t)NHD * INCH * 2);
    unsigned short* w2thi = (unsigned short*)carve((size_t)NHD * NHD * 2);
    unsigned short* w2tlo = (unsigned short*)carve((size_t)NHD * NHD * 2);

    const int egrid = (E_EDGES + 255) / 256;
    const int ngrid = (N_NODES + 255) / 256;

    // ---- CSR build + weight/input split (independent of layer compute) ----
    hipMemsetAsync(counts, 0, (size_t)N_NODES * 4, stream);
    hist_kernel<<<egrid, 256, 0, stream>>>(ei, counts);
    scan_local_kernel<<<NSCB, SBLK, 0, stream>>>(counts, offsets, bsum);
    scan_final_kernel<<<NSCB, SBLK, 0, stream>>>(offsets, cursor, bsum);
    scatter_kernel<<<egrid, 256, 0, stream>>>(ei, cursor, csr);
    graph_offsets_kernel<<<ngrid, 256, 0, stream>>>(batch, goff);
    wsplit_kernel<<<(INCH * NHD + 255) / 256, 256, 0, stream>>>(W1, w1thi, w1tlo, INCH);
    wsplit_kernel<<<(NHD * NHD + 255) / 256, 256, 0, stream>>>(W2, w2thi, w2tlo, NHD);
    asplit_kernel<<<(N_NODES * INCH + 255) / 256, 256, 0, stream>>>(x, xhi, xlo, N_NODES * INCH);

    dim3 ggrid((M_PAD + 127) / 128, NHD / 128);

    // ---- layer 1 ----
    gemm_mfma<<<ggrid, 256, 0, stream>>>(xhi, xlo, w1thi, w1tlo, a1s, a1d,
                                         ghi, es, ed, N_NODES, INCH);
    aggregate_fused<<<(N_NODES + 3) / 4, 256, 0, stream>>>(ghi, ei, csr, offsets,
                                                           es, ed, b1, h1hi, h1lo);
    // ---- layer 2 ----
    gemm_mfma<<<ggrid, 256, 0, stream>>>(h1hi, h1lo, w2thi, w2tlo, a2s, a2d,
                                         ghi, es, ed, N_NODES, NHD);
    aggregate_fused<<<(N_NODES + 3) / 4, 256, 0, stream>>>(ghi, ei, csr, offsets,
                                                           es, ed, b2, h2hi, nullptr);

    // ---- pooling + MLP ----
    hipMemsetAsync(psums, 0, (size_t)NGRAPH * DCAT * 4, stream);
    pool_sum_kernel<<<(N_NODES + PRB - 1) / PRB, 640, 0, stream>>>(x, h1hi, h2hi, batch, psums);
    pool_finalize_kernel<<<(NGRAPH * DCAT + 255) / 256, 256, 0, stream>>>(psums, goff, pooled);
    mlp_kernel<<<NGRAPH, 256, 0, stream>>>(pooled, W3, b3, W4, b4, out);
}

// Round 10
// 493.347 us; speedup vs baseline: 1.7316x; 1.0216x over previous
//
#include <hip/hip_runtime.h>
#include <cstdint>
#include <cstddef>

#define N_NODES 50000
#define M_PAD 50048    // 391 * 128, covers GEMM tile over-read
#define E_EDGES 800000
#define INCH 128
#define HID 64
#define HEADS 4
#define NHD 256      // HEADS*HID
#define NGRAPH 64
#define DCAT 640     // 128 + 256 + 256
#define NEG_SLOPE 0.2f

typedef __attribute__((ext_vector_type(8))) short bf16x8;
typedef __attribute__((ext_vector_type(4))) float f32x4;

// round-to-nearest-even fp32 -> bf16 bits
static __device__ inline unsigned short f2bf(float f) {
    unsigned int u = __float_as_uint(f);
    unsigned int r = (u + 0x7FFFu + ((u >> 16) & 1u)) >> 16;
    return (unsigned short)r;
}
static __device__ inline float bf2f(unsigned short b) {
    return __uint_as_float(((unsigned int)b) << 16);
}

// ------- fused pre-split: W1,W2 (transpose) + x (flat) -> hi/lo bf16 ---------
#define W1N (INCH * NHD)            // 32768
#define W2N (NHD * NHD)             // 65536
#define XN  (N_NODES * INCH)        // 6.4M
__global__ void split_all_kernel(
    const float* __restrict__ W1, const float* __restrict__ W2,
    const float* __restrict__ x,
    unsigned short* __restrict__ w1thi, unsigned short* __restrict__ w1tlo,
    unsigned short* __restrict__ w2thi, unsigned short* __restrict__ w2tlo,
    unsigned short* __restrict__ xhi, unsigned short* __restrict__ xlo)
{
    const int i = blockIdx.x * 256 + threadIdx.x;
    float v; unsigned short* dhi; unsigned short* dlo; int idx;
    if (i < W1N) {
        const int n = i / INCH, k = i - n * INCH;
        v = W1[(size_t)k * NHD + n]; dhi = w1thi; dlo = w1tlo; idx = i;
    } else if (i < W1N + W2N) {
        const int j = i - W1N;
        const int n = j / NHD, k = j - n * NHD;
        v = W2[(size_t)k * NHD + n]; dhi = w2thi; dlo = w2tlo; idx = j;
    } else {
        const int j = i - W1N - W2N;
        if (j >= XN) return;
        v = x[j]; dhi = xhi; dlo = xlo; idx = j;
    }
    const unsigned short h = f2bf(v);
    dhi[idx] = h;
    dlo[idx] = f2bf(v - bf2f(h));
}

// ---------------- MFMA GEMM: Cb[M,256](bf16) = (Ahi+Alo) @ (Bhi+Blo) ---------
// All operands pre-split bf16: staging is pure 16B copies (no conversion VALU).
// Fused epilogue: es/ed per-head dots (wave's 64x64 fragment = one head).
#define GK 64
#define LDAB 72   // LDS row stride in elements (144B: b128 reads 2-way = free)

__global__ __launch_bounds__(256, 2) void gemm_mfma(
    const unsigned short* __restrict__ Athi,
    const unsigned short* __restrict__ Atlo,
    const unsigned short* __restrict__ Bthi,
    const unsigned short* __restrict__ Btlo,
    const float* __restrict__ asrc, const float* __restrict__ adst,
    unsigned short* __restrict__ Cb, float* __restrict__ es,
    float* __restrict__ ed, int M, int K)
{
    __shared__ unsigned short Ahi[128 * LDAB];
    __shared__ unsigned short Alo[128 * LDAB];
    __shared__ unsigned short Bhi[128 * LDAB];
    __shared__ unsigned short Blo[128 * LDAB];

    const int t    = threadIdx.x;
    const int row0 = blockIdx.x * 128;
    const int col0 = blockIdx.y * 128;
    const int wave = t >> 6, lane = t & 63;
    const int wr = (wave >> 1) * 64;
    const int wc = (wave & 1) * 64;
    const int m16 = lane & 15, quad = lane >> 4;

    f32x4 acc[4][4];
#pragma unroll
    for (int i = 0; i < 4; ++i)
#pragma unroll
        for (int j = 0; j < 4; ++j) acc[i][j] = (f32x4){0.f, 0.f, 0.f, 0.f};

    for (int k0 = 0; k0 < K; k0 += GK) {
        // ---- stage: A tile 128x64 + B tile 128x64, hi+lo, pure 16B copies ----
#pragma unroll
        for (int i = 0; i < 4; ++i) {
            const int seg = t + i * 256;       // 1024 segments of 8 bf16
            const int r = seg >> 3, p = (seg & 7) * 8;
            const size_t ga = (size_t)(row0 + r) * K + k0 + p;
            const size_t gb = (size_t)(col0 + r) * K + k0 + p;
            *(int4*)(&Ahi[r * LDAB + p]) = *(const int4*)(Athi + ga);
            *(int4*)(&Alo[r * LDAB + p]) = *(const int4*)(Atlo + ga);
            *(int4*)(&Bhi[r * LDAB + p]) = *(const int4*)(Bthi + gb);
            *(int4*)(&Blo[r * LDAB + p]) = *(const int4*)(Btlo + gb);
        }
        __syncthreads();

#pragma unroll
        for (int h = 0; h < 2; ++h) {
            bf16x8 afh[4], afl[4], bfh[4], bfl[4];
#pragma unroll
            for (int i = 0; i < 4; ++i) {
                const int r = wr + i * 16 + m16;
                afh[i] = *(const bf16x8*)(&Ahi[r * LDAB + h * 32 + quad * 8]);
                afl[i] = *(const bf16x8*)(&Alo[r * LDAB + h * 32 + quad * 8]);
            }
#pragma unroll
            for (int j = 0; j < 4; ++j) {
                const int n = wc + j * 16 + m16;
                bfh[j] = *(const bf16x8*)(&Bhi[n * LDAB + h * 32 + quad * 8]);
                bfl[j] = *(const bf16x8*)(&Blo[n * LDAB + h * 32 + quad * 8]);
            }
#pragma unroll
            for (int i = 0; i < 4; ++i)
#pragma unroll
                for (int j = 0; j < 4; ++j) {
                    acc[i][j] = __builtin_amdgcn_mfma_f32_16x16x32_bf16(afh[i], bfh[j], acc[i][j], 0, 0, 0);
                    acc[i][j] = __builtin_amdgcn_mfma_f32_16x16x32_bf16(afh[i], bfl[j], acc[i][j], 0, 0, 0);
                    acc[i][j] = __builtin_amdgcn_mfma_f32_16x16x32_bf16(afl[i], bfh[j], acc[i][j], 0, 0, 0);
                }
        }
        __syncthreads();
    }

    // ---- epilogue 1: bf16 C store (C/D layout col=lane&15, row=quad*4+reg)
#pragma unroll
    for (int i = 0; i < 4; ++i)
#pragma unroll
        for (int reg = 0; reg < 4; ++reg) {
            const int r = row0 + wr + i * 16 + quad * 4 + reg;
            if (r < M) {
#pragma unroll
                for (int j = 0; j < 4; ++j)
                    Cb[(size_t)r * NHD + col0 + wc + j * 16 + m16] = f2bf(acc[i][j][reg]);
            }
        }

    // ---- epilogue 2: fused attention coefficients for this wave's head ----
    const int head = (col0 + wc) >> 6;
    float a_s[4], a_d[4];
#pragma unroll
    for (int j = 0; j < 4; ++j) {
        a_s[j] = asrc[head * HID + j * 16 + m16];
        a_d[j] = adst[head * HID + j * 16 + m16];
    }
#pragma unroll
    for (int i = 0; i < 4; ++i)
#pragma unroll
        for (int reg = 0; reg < 4; ++reg) {
            float ps = 0.f, pd = 0.f;
#pragma unroll
            for (int j = 0; j < 4; ++j) {
                const float v = acc[i][j][reg];
                ps += v * a_s[j];
                pd += v * a_d[j];
            }
#pragma unroll
            for (int off = 1; off < 16; off <<= 1) {
                ps += __shfl_xor(ps, off, 64);
                pd += __shfl_xor(pd, off, 64);
            }
            if (m16 == 0) {
                const int r = row0 + wr + i * 16 + quad * 4 + reg;
                if (r < M) {
                    es[r * HEADS + head] = ps;
                    ed[r * HEADS + head] = pd;
                }
            }
        }
}

// ------------------------------ CSR build -----------------------------------
__global__ void hist_kernel(const int* __restrict__ ei, int* __restrict__ counts)
{
    const int e = blockIdx.x * 256 + threadIdx.x;
    if (e >= E_EDGES) return;
    atomicAdd(&counts[ei[E_EDGES + e]], 1);
}

#define SBLK 1024
#define NSCB ((N_NODES + SBLK - 1) / SBLK)   // 49

__global__ __launch_bounds__(1024) void scan_local_kernel(
    const int* __restrict__ counts, int* __restrict__ offsets,
    int* __restrict__ bsum)
{
    __shared__ int tmp[SBLK];
    const int t = threadIdx.x;
    const int i = blockIdx.x * SBLK + t;
    const int v = (i < N_NODES) ? counts[i] : 0;
    tmp[t] = v;
    __syncthreads();
    for (int off = 1; off < SBLK; off <<= 1) {
        const int u = (t >= off) ? tmp[t - off] : 0;
        __syncthreads();
        tmp[t] += u;
        __syncthreads();
    }
    if (i < N_NODES) offsets[i] = tmp[t] - v;    // local exclusive prefix
    if (t == SBLK - 1) bsum[blockIdx.x] = tmp[t];
}

__global__ __launch_bounds__(1024) void scan_final_kernel(
    int* __restrict__ offsets, int* __restrict__ cursor,
    const int* __restrict__ bsum)
{
    __shared__ int base_sh;
    const int b = blockIdx.x;
    if (threadIdx.x == 0) {
        int s = 0;
        for (int j = 0; j < b; ++j) s += bsum[j];
        base_sh = s;
    }
    __syncthreads();
    const int i = b * SBLK + threadIdx.x;
    if (i < N_NODES) {
        const int v = offsets[i] + base_sh;
        offsets[i] = v;
        cursor[i]  = v;
    }
    if (b == 0 && threadIdx.x == 0) offsets[N_NODES] = E_EDGES;
}

__global__ void scatter_kernel(const int* __restrict__ ei, int* __restrict__ cursor,
                               int* __restrict__ csr)
{
    const int e = blockIdx.x * 256 + threadIdx.x;
    if (e >= E_EDGES) return;
    const int d = ei[E_EDGES + e];
    const int pos = atomicAdd(&cursor[d], 1);
    csr[pos] = e;
}

// ------- fused softmax + aggregation: one wave per dst node ------------------
// v4: two edges per wave-iteration -- lanes 0-31 process even edges, lanes
// 32-63 odd edges, each lane loading bf16x8 (16B, 8 cols). Halves VMEM
// instruction count vs 8B/lane. Cross-half combine: 9 shfl_xor at the end.
__global__ __launch_bounds__(256) void aggregate_fused(
    const unsigned short* __restrict__ hb, const int* __restrict__ ei,
    const int* __restrict__ csr, const int* __restrict__ offsets,
    const float* __restrict__ es, const float* __restrict__ ed,
    const float* __restrict__ bias, unsigned short* __restrict__ outhi,
    unsigned short* __restrict__ outlo)
{
    const int wid  = threadIdx.x >> 6;
    const int lane = threadIdx.x & 63;
    const int node = blockIdx.x * 4 + wid;
    if (node >= N_NODES) return;
    const int head_p = lane >> 4;        // head for weight preload
    const int sub    = lane & 15;        // edge slot within 16-edge chunk
    const int half   = lane >> 5;        // 0: even edges, 1: odd edges
    const int hl     = lane & 31;
    const int col8   = hl * 8;           // 8 consecutive cols per lane
    const int widx   = (hl >> 3) << 4;   // shfl base for my head's weights

    const float edc = ed[node * 4 + head_p];
    const int beg = offsets[node], end = offsets[node + 1];

    float acc[8];
#pragma unroll
    for (int k = 0; k < 8; ++k) acc[k] = 0.f;
    float dsum = 0.f;

    int base = beg;
    int m_cur = min(16, end - base);
    int s_cur = 0; float w_cur = 0.f;
    if (base < end && sub < m_cur) {
        const int eid = csr[base + sub];
        s_cur = ei[eid];
        float u = es[s_cur * 4 + head_p] + edc;
        u = u > 0.f ? u : NEG_SLOPE * u;
        w_cur = expf(u);
    }

    while (base < end) {
        const int base_n = base + 16;
        const int m_nxt = min(16, end - base_n);
        int s_nxt = 0; float w_nxt = 0.f;
        if (base_n < end && sub < m_nxt) {
            const int eid = csr[base_n + sub];
            s_nxt = ei[eid];
            float u = es[s_nxt * 4 + head_p] + edc;
            u = u > 0.f ? u : NEG_SLOPE * u;
            w_nxt = expf(u);
        }
        // consume current chunk, 2 edges per iteration (w==0 past m_cur)
        if (m_cur == 16) {
#pragma unroll
            for (int i = 0; i < 16; i += 2) {
                const int e0 = i + half;
                const int   s = __shfl(s_cur, e0, 64);
                const float w = __shfl(w_cur, widx + e0, 64);
                const bf16x8 v = *(const bf16x8*)(hb + (size_t)s * NHD + col8);
#pragma unroll
                for (int k = 0; k < 8; ++k)
                    acc[k] += w * bf2f((unsigned short)v[k]);
                dsum += w;
            }
        } else {
            for (int i = 0; i < m_cur; i += 2) {
                const int e0 = i + half;
                const int   s = __shfl(s_cur, e0 & 15, 64);
                const float w = __shfl(w_cur, widx + (e0 & 15), 64);
                const bf16x8 v = *(const bf16x8*)(hb + (size_t)s * NHD + col8);
                const float we = (e0 < m_cur) ? w : 0.f;
#pragma unroll
                for (int k = 0; k < 8; ++k)
                    acc[k] += we * bf2f((unsigned short)v[k]);
                dsum += we;
            }
        }
        s_cur = s_nxt; w_cur = w_nxt; m_cur = m_nxt; base = base_n;
    }

    // combine even/odd halves (lane l and l^32 hold the same 8 cols)
    dsum += __shfl_xor(dsum, 32, 64);
#pragma unroll
    for (int k = 0; k < 8; ++k) acc[k] += __shfl_xor(acc[k], 32, 64);

    const float inv = 1.0f / (dsum + 1e-16f);
    const float4 bb0 = *(const float4*)(bias + col8);
    const float4 bb1 = *(const float4*)(bias + col8 + 4);
    float o[8];
    o[0] = fmaxf(acc[0] * inv + bb0.x, 0.f);
    o[1] = fmaxf(acc[1] * inv + bb0.y, 0.f);
    o[2] = fmaxf(acc[2] * inv + bb0.z, 0.f);
    o[3] = fmaxf(acc[3] * inv + bb0.w, 0.f);
    o[4] = fmaxf(acc[4] * inv + bb1.x, 0.f);
    o[5] = fmaxf(acc[5] * inv + bb1.y, 0.f);
    o[6] = fmaxf(acc[6] * inv + bb1.z, 0.f);
    o[7] = fmaxf(acc[7] * inv + bb1.w, 0.f);

    bf16x8 hi8;
#pragma unroll
    for (int k = 0; k < 8; ++k) hi8[k] = (short)f2bf(o[k]);
    if (half == 0) {
        *(bf16x8*)(outhi + (size_t)node * NHD + col8) = hi8;
    } else if (outlo) {
        bf16x8 lo8;
#pragma unroll
        for (int k = 0; k < 8; ++k)
            lo8[k] = (short)f2bf(o[k] - bf2f((unsigned short)hi8[k]));
        *(bf16x8*)(outlo + (size_t)node * NHD + col8) = lo8;
    }
}

// ------------------------------ pooling -------------------------------------
__global__ void graph_offsets_kernel(const int* __restrict__ batch, int* __restrict__ goff)
{
    const int n = blockIdx.x * 256 + threadIdx.x;
    if (n >= N_NODES) return;
    const int b  = batch[n];
    const int bp = (n == 0) ? -1 : batch[n - 1];
    for (int g = bp + 1; g <= b; ++g) goff[g] = n;
    if (n == N_NODES - 1) {
        for (int g = b + 1; g <= NGRAPH; ++g) goff[g] = N_NODES;
    }
}

#define PRB 128

__global__ __launch_bounds__(640) void pool_sum_kernel(
    const float* __restrict__ x, const unsigned short* __restrict__ h1b,
    const unsigned short* __restrict__ h2b, const int* __restrict__ batch,
    float* __restrict__ sums)
{
    __shared__ int bsh[PRB];
    const int c  = threadIdx.x;            // 0..639
    const int r0 = blockIdx.x * PRB;
    const int r1 = min(N_NODES, r0 + PRB);
    const int nr = r1 - r0;
    if (c < nr) bsh[c] = batch[r0 + c];
    __syncthreads();

    const float* srcf = nullptr;
    const unsigned short* srcb = nullptr;
    int ld, cc;
    if (c < INCH)            { srcf = x;   ld = INCH; cc = c; }
    else if (c < INCH + NHD) { srcb = h1b; ld = NHD;  cc = c - INCH; }
    else                     { srcb = h2b; ld = NHD;  cc = c - INCH - NHD; }

    float sum = 0.f;
    int g = bsh[0];
    for (int i = 0; i < nr; ++i) {
        const int gb = bsh[i];
        if (gb != g) {
            atomicAdd(&sums[g * DCAT + c], sum);
            sum = 0.f;
            g = gb;
        }
        sum += srcf ? srcf[(size_t)(r0 + i) * ld + cc]
                    : bf2f(srcb[(size_t)(r0 + i) * ld + cc]);
    }
    atomicAdd(&sums[g * DCAT + c], sum);
}

// ------------------------------ MLP head (reads psums directly) --------------
__global__ __launch_bounds__(256) void mlp_kernel(
    const float* __restrict__ psums, const int* __restrict__ goff,
    const float* __restrict__ W3, const float* __restrict__ b3,
    const float* __restrict__ W4, const float* __restrict__ b4,
    float* __restrict__ out)
{
    const int g = blockIdx.x;
    __shared__ float p[DCAT];
    __shared__ float hm[256];
    const float inv = 1.0f / fmaxf((float)(goff[g + 1] - goff[g]), 1.0f);
    for (int i = threadIdx.x; i < DCAT; i += 256)
        p[i] = psums[(size_t)g * DCAT + i] * inv;
    __syncthreads();
    float s = b3[threadIdx.x];
    for (int k = 0; k < DCAT; ++k) s += p[k] * W3[(size_t)k * 256 + threadIdx.x];
    hm[threadIdx.x] = fmaxf(s, 0.f);
    __syncthreads();
    if (threadIdx.x < 128) {
        float o = b4[threadIdx.x];
        for (int k = 0; k < 256; ++k) o += hm[k] * W4[(size_t)k * 128 + threadIdx.x];
        out[(size_t)g * 128 + threadIdx.x] = o;
    }
}

// ------------------------------ launch --------------------------------------
extern "C" void kernel_launch(void* const* d_in, const int* in_sizes, int n_in,
                              void* d_out, int out_size, void* d_ws, size_t ws_size,
                              hipStream_t stream)
{
    const float* x     = (const float*)d_in[0];
    const int*   ei    = (const int*)d_in[1];
    const int*   batch = (const int*)d_in[2];
    const float* W1    = (const float*)d_in[3];
    const float* a1s   = (const float*)d_in[4];
    const float* a1d   = (const float*)d_in[5];
    const float* b1    = (const float*)d_in[6];
    const float* W2    = (const float*)d_in[7];
    const float* a2s   = (const float*)d_in[8];
    const float* a2d   = (const float*)d_in[9];
    const float* b2    = (const float*)d_in[10];
    const float* W3    = (const float*)d_in[11];
    const float* b3    = (const float*)d_in[12];
    const float* W4    = (const float*)d_in[13];
    const float* b4    = (const float*)d_in[14];
    float* out = (float*)d_out;

    // workspace carve
    size_t off = 0;
    auto carve = [&](size_t bytes) -> void* {
        void* p = (char*)d_ws + off;
        off = (off + bytes + 255) & ~(size_t)255;
        return p;
    };
    unsigned short* xhi   = (unsigned short*)carve((size_t)M_PAD * INCH * 2);
    unsigned short* xlo   = (unsigned short*)carve((size_t)M_PAD * INCH * 2);
    unsigned short* ghi   = (unsigned short*)carve((size_t)N_NODES * NHD * 2);  // GEMM out (gather src)
    unsigned short* h1hi  = (unsigned short*)carve((size_t)M_PAD * NHD * 2);
    unsigned short* h1lo  = (unsigned short*)carve((size_t)M_PAD * NHD * 2);
    unsigned short* h2hi  = (unsigned short*)carve((size_t)N_NODES * NHD * 2);
    float* es     = (float*)carve((size_t)N_NODES * HEADS * 4);
    float* ed     = (float*)carve((size_t)N_NODES * HEADS * 4);
    float* psums  = (float*)carve((size_t)NGRAPH * DCAT * 4);
    int*   counts  = (int*)carve((size_t)N_NODES * 4);
    int*   offsets = (int*)carve((size_t)(N_NODES + 1) * 4);
    int*   cursor  = (int*)carve((size_t)N_NODES * 4);
    int*   csr     = (int*)carve((size_t)E_EDGES * 4);
    int*   goff    = (int*)carve((size_t)(NGRAPH + 1) * 4);
    int*   bsum    = (int*)carve((size_t)NSCB * 4);
    unsigned short* w1thi = (unsigned short*)carve((size_t)NHD * INCH * 2);
    unsigned short* w1tlo = (unsigned short*)carve((size_t)NHD * INCH * 2);
    unsigned short* w2thi = (unsigned short*)carve((size_t)NHD * NHD * 2);
    unsigned short* w2tlo = (unsigned short*)carve((size_t)NHD * NHD * 2);

    const int egrid = (E_EDGES + 255) / 256;
    const int ngrid = (N_NODES + 255) / 256;

    // ---- CSR build + weight/input split (independent of layer compute) ----
    hipMemsetAsync(counts, 0, (size_t)N_NODES * 4, stream);
    hist_kernel<<<egrid, 256, 0, stream>>>(ei, counts);
    scan_local_kernel<<<NSCB, SBLK, 0, stream>>>(counts, offsets, bsum);
    scan_final_kernel<<<NSCB, SBLK, 0, stream>>>(offsets, cursor, bsum);
    scatter_kernel<<<egrid, 256, 0, stream>>>(ei, cursor, csr);
    graph_offsets_kernel<<<ngrid, 256, 0, stream>>>(batch, goff);
    split_all_kernel<<<(W1N + W2N + XN + 255) / 256, 256, 0, stream>>>(
        W1, W2, x, w1thi, w1tlo, w2thi, w2tlo, xhi, xlo);

    dim3 ggrid((M_PAD + 127) / 128, NHD / 128);

    // ---- layer 1 ----
    gemm_mfma<<<ggrid, 256, 0, stream>>>(xhi, xlo, w1thi, w1tlo, a1s, a1d,
                                         ghi, es, ed, N_NODES, INCH);
    aggregate_fused<<<(N_NODES + 3) / 4, 256, 0, stream>>>(ghi, ei, csr, offsets,
                                                           es, ed, b1, h1hi, h1lo);
    // ---- layer 2 ----
    gemm_mfma<<<ggrid, 256, 0, stream>>>(h1hi, h1lo, w2thi, w2tlo, a2s, a2d,
                                         ghi, es, ed, N_NODES, NHD);
    aggregate_fused<<<(N_NODES + 3) / 4, 256, 0, stream>>>(ghi, ei, csr, offsets,
                                                           es, ed, b2, h2hi, nullptr);

    // ---- pooling + MLP ----
    hipMemsetAsync(psums, 0, (size_t)NGRAPH * DCAT * 4, stream);
    pool_sum_kernel<<<(N_NODES + PRB - 1) / PRB, 640, 0, stream>>>(x, h1hi, h2hi, batch, psums);
    mlp_kernel<<<NGRAPH, 256, 0, stream>>>(psums, goff, W3, b3, W4, b4, out);
}

// Round 11
// 486.553 us; speedup vs baseline: 1.7557x; 1.0140x over previous
//
#include <hip/hip_runtime.h>
#include <cstdint>
#include <cstddef>

#define N_NODES 50000
#define M_PAD 50048    // 391 * 128, covers GEMM tile over-read
#define E_EDGES 800000
#define INCH 128
#define HID 64
#define HEADS 4
#define NHD 256      // HEADS*HID
#define NGRAPH 64
#define DCAT 640     // 128 + 256 + 256
#define NEG_SLOPE 0.2f

typedef __attribute__((ext_vector_type(8))) short bf16x8;
typedef __attribute__((ext_vector_type(4))) float f32x4;

// round-to-nearest-even fp32 -> bf16 bits
static __device__ inline unsigned short f2bf(float f) {
    unsigned int u = __float_as_uint(f);
    unsigned int r = (u + 0x7FFFu + ((u >> 16) & 1u)) >> 16;
    return (unsigned short)r;
}
static __device__ inline float bf2f(unsigned short b) {
    return __uint_as_float(((unsigned int)b) << 16);
}

// ---- fused preamble: hist + graph_offsets + psums-zero + hi/lo splits -------
#define W1N (INCH * NHD)            // 32768
#define W2N (NHD * NHD)             // 65536
#define XN  (N_NODES * INCH)        // 6.4M
#define HB  ((E_EDGES + 255) / 256)           // 3125 hist blocks
#define GB  ((N_NODES + 255) / 256)           // 196 graph_offsets blocks
#define PZB ((NGRAPH * DCAT + 255) / 256)     // 160 psums-zero blocks
#define SPB ((W1N + W2N + XN + 255) / 256)    // 25384 split blocks
#define PREPB (HB + GB + PZB + SPB)

__global__ void prep_kernel(
    const int* __restrict__ ei, const int* __restrict__ batch,
    const float* __restrict__ W1, const float* __restrict__ W2,
    const float* __restrict__ x,
    int* __restrict__ counts, int* __restrict__ goff,
    float* __restrict__ psums,
    unsigned short* __restrict__ w1thi, unsigned short* __restrict__ w1tlo,
    unsigned short* __restrict__ w2thi, unsigned short* __restrict__ w2tlo,
    unsigned short* __restrict__ xhi, unsigned short* __restrict__ xlo)
{
    const int b = blockIdx.x;
    if (b < HB) {                               // ---- histogram of dst ----
        const int e = b * 256 + threadIdx.x;
        if (e < E_EDGES) atomicAdd(&counts[ei[E_EDGES + e]], 1);
        return;
    }
    if (b < HB + GB) {                          // ---- graph offsets ----
        const int n = (b - HB) * 256 + threadIdx.x;
        if (n >= N_NODES) return;
        const int bb = batch[n];
        const int bp = (n == 0) ? -1 : batch[n - 1];
        for (int g = bp + 1; g <= bb; ++g) goff[g] = n;
        if (n == N_NODES - 1)
            for (int g = bb + 1; g <= NGRAPH; ++g) goff[g] = N_NODES;
        return;
    }
    if (b < HB + GB + PZB) {                    // ---- zero psums ----
        const int i = (b - HB - GB) * 256 + threadIdx.x;
        if (i < NGRAPH * DCAT) psums[i] = 0.f;
        return;
    }
    // ---- hi/lo splits: W1^T, W2^T, x ----
    const int i = (b - HB - GB - PZB) * 256 + threadIdx.x;
    float v; unsigned short* dhi; unsigned short* dlo; int idx;
    if (i < W1N) {
        const int n = i / INCH, k = i - n * INCH;
        v = W1[(size_t)k * NHD + n]; dhi = w1thi; dlo = w1tlo; idx = i;
    } else if (i < W1N + W2N) {
        const int j = i - W1N;
        const int n = j / NHD, k = j - n * NHD;
        v = W2[(size_t)k * NHD + n]; dhi = w2thi; dlo = w2tlo; idx = j;
    } else {
        const int j = i - W1N - W2N;
        if (j >= XN) return;
        v = x[j]; dhi = xhi; dlo = xlo; idx = j;
    }
    const unsigned short h = f2bf(v);
    dhi[idx] = h;
    dlo[idx] = f2bf(v - bf2f(h));
}

// ---------------- MFMA GEMM: Cb[M,256](bf16) = (Ahi+Alo) @ (Bhi+Blo) ---------
#define GK 64
#define LDAB 72   // LDS row stride in elements (144B: b128 reads 2-way = free)

__global__ __launch_bounds__(256, 2) void gemm_mfma(
    const unsigned short* __restrict__ Athi,
    const unsigned short* __restrict__ Atlo,
    const unsigned short* __restrict__ Bthi,
    const unsigned short* __restrict__ Btlo,
    const float* __restrict__ asrc, const float* __restrict__ adst,
    unsigned short* __restrict__ Cb, float* __restrict__ es,
    float* __restrict__ ed, int M, int K)
{
    __shared__ unsigned short Ahi[128 * LDAB];
    __shared__ unsigned short Alo[128 * LDAB];
    __shared__ unsigned short Bhi[128 * LDAB];
    __shared__ unsigned short Blo[128 * LDAB];

    const int t    = threadIdx.x;
    const int row0 = blockIdx.x * 128;
    const int col0 = blockIdx.y * 128;
    const int wave = t >> 6, lane = t & 63;
    const int wr = (wave >> 1) * 64;
    const int wc = (wave & 1) * 64;
    const int m16 = lane & 15, quad = lane >> 4;

    f32x4 acc[4][4];
#pragma unroll
    for (int i = 0; i < 4; ++i)
#pragma unroll
        for (int j = 0; j < 4; ++j) acc[i][j] = (f32x4){0.f, 0.f, 0.f, 0.f};

    for (int k0 = 0; k0 < K; k0 += GK) {
#pragma unroll
        for (int i = 0; i < 4; ++i) {
            const int seg = t + i * 256;       // 1024 segments of 8 bf16
            const int r = seg >> 3, p = (seg & 7) * 8;
            const size_t ga = (size_t)(row0 + r) * K + k0 + p;
            const size_t gb = (size_t)(col0 + r) * K + k0 + p;
            *(int4*)(&Ahi[r * LDAB + p]) = *(const int4*)(Athi + ga);
            *(int4*)(&Alo[r * LDAB + p]) = *(const int4*)(Atlo + ga);
            *(int4*)(&Bhi[r * LDAB + p]) = *(const int4*)(Bthi + gb);
            *(int4*)(&Blo[r * LDAB + p]) = *(const int4*)(Btlo + gb);
        }
        __syncthreads();

#pragma unroll
        for (int h = 0; h < 2; ++h) {
            bf16x8 afh[4], afl[4], bfh[4], bfl[4];
#pragma unroll
            for (int i = 0; i < 4; ++i) {
                const int r = wr + i * 16 + m16;
                afh[i] = *(const bf16x8*)(&Ahi[r * LDAB + h * 32 + quad * 8]);
                afl[i] = *(const bf16x8*)(&Alo[r * LDAB + h * 32 + quad * 8]);
            }
#pragma unroll
            for (int j = 0; j < 4; ++j) {
                const int n = wc + j * 16 + m16;
                bfh[j] = *(const bf16x8*)(&Bhi[n * LDAB + h * 32 + quad * 8]);
                bfl[j] = *(const bf16x8*)(&Blo[n * LDAB + h * 32 + quad * 8]);
            }
#pragma unroll
            for (int i = 0; i < 4; ++i)
#pragma unroll
                for (int j = 0; j < 4; ++j) {
                    acc[i][j] = __builtin_amdgcn_mfma_f32_16x16x32_bf16(afh[i], bfh[j], acc[i][j], 0, 0, 0);
                    acc[i][j] = __builtin_amdgcn_mfma_f32_16x16x32_bf16(afh[i], bfl[j], acc[i][j], 0, 0, 0);
                    acc[i][j] = __builtin_amdgcn_mfma_f32_16x16x32_bf16(afl[i], bfh[j], acc[i][j], 0, 0, 0);
                }
        }
        __syncthreads();
    }

    // ---- epilogue 1: bf16 C store (C/D layout col=lane&15, row=quad*4+reg)
#pragma unroll
    for (int i = 0; i < 4; ++i)
#pragma unroll
        for (int reg = 0; reg < 4; ++reg) {
            const int r = row0 + wr + i * 16 + quad * 4 + reg;
            if (r < M) {
#pragma unroll
                for (int j = 0; j < 4; ++j)
                    Cb[(size_t)r * NHD + col0 + wc + j * 16 + m16] = f2bf(acc[i][j][reg]);
            }
        }

    // ---- epilogue 2: fused attention coefficients for this wave's head ----
    const int head = (col0 + wc) >> 6;
    float a_s[4], a_d[4];
#pragma unroll
    for (int j = 0; j < 4; ++j) {
        a_s[j] = asrc[head * HID + j * 16 + m16];
        a_d[j] = adst[head * HID + j * 16 + m16];
    }
#pragma unroll
    for (int i = 0; i < 4; ++i)
#pragma unroll
        for (int reg = 0; reg < 4; ++reg) {
            float ps = 0.f, pd = 0.f;
#pragma unroll
            for (int j = 0; j < 4; ++j) {
                const float v = acc[i][j][reg];
                ps += v * a_s[j];
                pd += v * a_d[j];
            }
#pragma unroll
            for (int off = 1; off < 16; off <<= 1) {
                ps += __shfl_xor(ps, off, 64);
                pd += __shfl_xor(pd, off, 64);
            }
            if (m16 == 0) {
                const int r = row0 + wr + i * 16 + quad * 4 + reg;
                if (r < M) {
                    es[r * HEADS + head] = ps;
                    ed[r * HEADS + head] = pd;
                }
            }
        }
}

// ------------------------------ CSR scan ------------------------------------
#define SBLK 1024
#define NSCB ((N_NODES + SBLK - 1) / SBLK)   // 49

__global__ __launch_bounds__(1024) void scan_local_kernel(
    const int* __restrict__ counts, int* __restrict__ offsets,
    int* __restrict__ bsum)
{
    __shared__ int tmp[SBLK];
    const int t = threadIdx.x;
    const int i = blockIdx.x * SBLK + t;
    const int v = (i < N_NODES) ? counts[i] : 0;
    tmp[t] = v;
    __syncthreads();
    for (int off = 1; off < SBLK; off <<= 1) {
        const int u = (t >= off) ? tmp[t - off] : 0;
        __syncthreads();
        tmp[t] += u;
        __syncthreads();
    }
    if (i < N_NODES) offsets[i] = tmp[t] - v;    // local exclusive prefix
    if (t == SBLK - 1) bsum[blockIdx.x] = tmp[t];
}

__global__ __launch_bounds__(1024) void scan_final_kernel(
    int* __restrict__ offsets, int* __restrict__ cursor,
    const int* __restrict__ bsum)
{
    __shared__ int base_sh;
    const int b = blockIdx.x;
    if (threadIdx.x == 0) {
        int s = 0;
        for (int j = 0; j < b; ++j) s += bsum[j];
        base_sh = s;
    }
    __syncthreads();
    const int i = b * SBLK + threadIdx.x;
    if (i < N_NODES) {
        const int v = offsets[i] + base_sh;
        offsets[i] = v;
        cursor[i]  = v;
    }
    if (b == 0 && threadIdx.x == 0) offsets[N_NODES] = E_EDGES;
}

// scatter: csr holds the SRC node id directly (drops the ei indirection in
// the aggregate's hot loop)
__global__ void scatter_kernel(const int* __restrict__ ei, int* __restrict__ cursor,
                               int* __restrict__ csr)
{
    const int e = blockIdx.x * 256 + threadIdx.x;
    if (e >= E_EDGES) return;
    const int s = ei[e];
    const int d = ei[E_EDGES + e];
    const int pos = atomicAdd(&cursor[d], 1);
    csr[pos] = s;
}

// ------- fused softmax + aggregation: one wave per dst node ------------------
// v3 structure (zero LDS-crossbar conflicts): 16-edge chunks, readlane-
// scalarized src row, next-chunk csr->es prefetch overlapped with gathers.
__global__ __launch_bounds__(256) void aggregate_fused(
    const unsigned short* __restrict__ hb, const int* __restrict__ csr,
    const int* __restrict__ offsets,
    const float* __restrict__ es, const float* __restrict__ ed,
    const float* __restrict__ bias, unsigned short* __restrict__ outhi,
    unsigned short* __restrict__ outlo)
{
    const int wid  = threadIdx.x >> 6;
    const int lane = threadIdx.x & 63;
    const int node = blockIdx.x * 4 + wid;
    if (node >= N_NODES) return;
    const int head = lane >> 4;          // col = lane*4 -> head = col/64
    const int col  = lane * 4;
    const int sub  = lane & 15;          // edge slot within 16-edge chunk

    const float edc = ed[node * 4 + head];
    const int beg = offsets[node], end = offsets[node + 1];

    float4 acc = make_float4(0.f, 0.f, 0.f, 0.f);
    float dsum = 0.f;

    int base = beg;
    int m_cur = min(16, end - base);
    int s_cur = 0; float w_cur = 0.f;
    if (base < end && sub < m_cur) {
        s_cur = csr[base + sub];
        float u = es[s_cur * 4 + head] + edc;
        u = u > 0.f ? u : NEG_SLOPE * u;
        w_cur = expf(u);
    }

    while (base < end) {
        const int base_n = base + 16;
        const int m_nxt = min(16, end - base_n);
        int s_nxt = 0; float w_nxt = 0.f;
        if (base_n < end && sub < m_nxt) {
            s_nxt = csr[base_n + sub];
            float u = es[s_nxt * 4 + head] + edc;
            u = u > 0.f ? u : NEG_SLOPE * u;
            w_nxt = expf(u);
        }
        if (m_cur == 16) {
#pragma unroll
            for (int i = 0; i < 16; ++i) {
                const int   s = (int)__builtin_amdgcn_readlane((unsigned)s_cur, i);
                const float w = __shfl(w_cur, (lane & 48) + i, 64);
                const ushort4 v = *(const ushort4*)(hb + (size_t)s * NHD + col);
                acc.x += w * bf2f(v.x);
                acc.y += w * bf2f(v.y);
                acc.z += w * bf2f(v.z);
                acc.w += w * bf2f(v.w);
                dsum += w;
            }
        } else {
            for (int i = 0; i < m_cur; ++i) {
                const int   s = __shfl(s_cur, i, 64);
                const float w = __shfl(w_cur, (lane & 48) + i, 64);
                const ushort4 v = *(const ushort4*)(hb + (size_t)s * NHD + col);
                acc.x += w * bf2f(v.x);
                acc.y += w * bf2f(v.y);
                acc.z += w * bf2f(v.z);
                acc.w += w * bf2f(v.w);
                dsum += w;
            }
        }
        s_cur = s_nxt; w_cur = w_nxt; m_cur = m_nxt; base = base_n;
    }

    const float inv = 1.0f / (dsum + 1e-16f);
    const float4 bb = *(const float4*)(bias + col);
    float4 o;
    o.x = fmaxf(acc.x * inv + bb.x, 0.f);
    o.y = fmaxf(acc.y * inv + bb.y, 0.f);
    o.z = fmaxf(acc.z * inv + bb.z, 0.f);
    o.w = fmaxf(acc.w * inv + bb.w, 0.f);
    ushort4 oh;
    oh.x = f2bf(o.x); oh.y = f2bf(o.y); oh.z = f2bf(o.z); oh.w = f2bf(o.w);
    *(ushort4*)(outhi + (size_t)node * NHD + col) = oh;
    if (outlo) {
        ushort4 ol;
        ol.x = f2bf(o.x - bf2f(oh.x));
        ol.y = f2bf(o.y - bf2f(oh.y));
        ol.z = f2bf(o.z - bf2f(oh.z));
        ol.w = f2bf(o.w - bf2f(oh.w));
        *(ushort4*)(outlo + (size_t)node * NHD + col) = ol;
    }
}

// ------------------------------ pooling (all-bf16 sources) -------------------
#define PRB 128

__global__ __launch_bounds__(640) void pool_sum_kernel(
    const unsigned short* __restrict__ xhi, const unsigned short* __restrict__ h1b,
    const unsigned short* __restrict__ h2b, const int* __restrict__ batch,
    float* __restrict__ sums)
{
    __shared__ int bsh[PRB];
    const int c  = threadIdx.x;            // 0..639
    const int r0 = blockIdx.x * PRB;
    const int r1 = min(N_NODES, r0 + PRB);
    const int nr = r1 - r0;
    if (c < nr) bsh[c] = batch[r0 + c];
    __syncthreads();

    const unsigned short* srcb; int ld, cc;
    if (c < INCH)            { srcb = xhi; ld = INCH; cc = c; }
    else if (c < INCH + NHD) { srcb = h1b; ld = NHD;  cc = c - INCH; }
    else                     { srcb = h2b; ld = NHD;  cc = c - INCH - NHD; }

    float sum = 0.f;
    int g = bsh[0];
    for (int i = 0; i < nr; ++i) {
        const int gb = bsh[i];
        if (gb != g) {
            atomicAdd(&sums[g * DCAT + c], sum);
            sum = 0.f;
            g = gb;
        }
        sum += bf2f(srcb[(size_t)(r0 + i) * ld + cc]);
    }
    atomicAdd(&sums[g * DCAT + c], sum);
}

// --------------- MLP head: 8 graphs per block, 8 blocks ----------------------
__global__ __launch_bounds__(256) void mlp_kernel(
    const float* __restrict__ psums, const int* __restrict__ goff,
    const float* __restrict__ W3, const float* __restrict__ b3,
    const float* __restrict__ W4, const float* __restrict__ b4,
    float* __restrict__ out)
{
    const int g0 = blockIdx.x * 8;
    __shared__ float p[8][DCAT];    // 20 KB
    __shared__ float hm[8][256];    // 8 KB
    for (int idx = threadIdx.x; idx < 8 * DCAT; idx += 256) {
        const int gg = idx / DCAT, i = idx - gg * DCAT;
        const int g = g0 + gg;
        const float inv = 1.0f / fmaxf((float)(goff[g + 1] - goff[g]), 1.0f);
        p[gg][i] = psums[(size_t)g * DCAT + i] * inv;
    }
    __syncthreads();
    const int c = threadIdx.x;
    float acc[8];
#pragma unroll
    for (int gg = 0; gg < 8; ++gg) acc[gg] = b3[c];
    for (int k = 0; k < DCAT; ++k) {
        const float w = W3[(size_t)k * 256 + c];
#pragma unroll
        for (int gg = 0; gg < 8; ++gg) acc[gg] += p[gg][k] * w;
    }
#pragma unroll
    for (int gg = 0; gg < 8; ++gg) hm[gg][c] = fmaxf(acc[gg], 0.f);
    __syncthreads();
    const int c2 = threadIdx.x & 127;
    const int gh = (threadIdx.x >> 7) * 4;   // 0 or 4
    float a2[4];
#pragma unroll
    for (int j = 0; j < 4; ++j) a2[j] = b4[c2];
    for (int k = 0; k < 256; ++k) {
        const float w = W4[(size_t)k * 128 + c2];
#pragma unroll
        for (int j = 0; j < 4; ++j) a2[j] += hm[gh + j][k] * w;
    }
#pragma unroll
    for (int j = 0; j < 4; ++j)
        out[(size_t)(g0 + gh + j) * 128 + c2] = a2[j];
}

// ------------------------------ launch --------------------------------------
extern "C" void kernel_launch(void* const* d_in, const int* in_sizes, int n_in,
                              void* d_out, int out_size, void* d_ws, size_t ws_size,
                              hipStream_t stream)
{
    const float* x     = (const float*)d_in[0];
    const int*   ei    = (const int*)d_in[1];
    const int*   batch = (const int*)d_in[2];
    const float* W1    = (const float*)d_in[3];
    const float* a1s   = (const float*)d_in[4];
    const float* a1d   = (const float*)d_in[5];
    const float* b1    = (const float*)d_in[6];
    const float* W2    = (const float*)d_in[7];
    const float* a2s   = (const float*)d_in[8];
    const float* a2d   = (const float*)d_in[9];
    const float* b2    = (const float*)d_in[10];
    const float* W3    = (const float*)d_in[11];
    const float* b3    = (const float*)d_in[12];
    const float* W4    = (const float*)d_in[13];
    const float* b4    = (const float*)d_in[14];
    float* out = (float*)d_out;

    // workspace carve
    size_t off = 0;
    auto carve = [&](size_t bytes) -> void* {
        void* p = (char*)d_ws + off;
        off = (off + bytes + 255) & ~(size_t)255;
        return p;
    };
    unsigned short* xhi   = (unsigned short*)carve((size_t)M_PAD * INCH * 2);
    unsigned short* xlo   = (unsigned short*)carve((size_t)M_PAD * INCH * 2);
    unsigned short* ghi   = (unsigned short*)carve((size_t)N_NODES * NHD * 2);  // GEMM out (gather src)
    unsigned short* h1hi  = (unsigned short*)carve((size_t)M_PAD * NHD * 2);
    unsigned short* h1lo  = (unsigned short*)carve((size_t)M_PAD * NHD * 2);
    unsigned short* h2hi  = (unsigned short*)carve((size_t)N_NODES * NHD * 2);
    float* es     = (float*)carve((size_t)N_NODES * HEADS * 4);
    float* ed     = (float*)carve((size_t)N_NODES * HEADS * 4);
    float* psums  = (float*)carve((size_t)NGRAPH * DCAT * 4);
    int*   counts  = (int*)carve((size_t)N_NODES * 4);
    int*   offsets = (int*)carve((size_t)(N_NODES + 1) * 4);
    int*   cursor  = (int*)carve((size_t)N_NODES * 4);
    int*   csr     = (int*)carve((size_t)E_EDGES * 4);
    int*   goff    = (int*)carve((size_t)(NGRAPH + 1) * 4);
    int*   bsum    = (int*)carve((size_t)NSCB * 4);
    unsigned short* w1thi = (unsigned short*)carve((size_t)NHD * INCH * 2);
    unsigned short* w1tlo = (unsigned short*)carve((size_t)NHD * INCH * 2);
    unsigned short* w2thi = (unsigned short*)carve((size_t)NHD * NHD * 2);
    unsigned short* w2tlo = (unsigned short*)carve((size_t)NHD * NHD * 2);

    const int egrid = (E_EDGES + 255) / 256;

    // ---- preamble: histogram + graph offsets + psums zero + splits ----
    hipMemsetAsync(counts, 0, (size_t)N_NODES * 4, stream);
    prep_kernel<<<PREPB, 256, 0, stream>>>(ei, batch, W1, W2, x,
                                           counts, goff, psums,
                                           w1thi, w1tlo, w2thi, w2tlo, xhi, xlo);
    scan_local_kernel<<<NSCB, SBLK, 0, stream>>>(counts, offsets, bsum);
    scan_final_kernel<<<NSCB, SBLK, 0, stream>>>(offsets, cursor, bsum);
    scatter_kernel<<<egrid, 256, 0, stream>>>(ei, cursor, csr);

    dim3 ggrid((M_PAD + 127) / 128, NHD / 128);

    // ---- layer 1 ----
    gemm_mfma<<<ggrid, 256, 0, stream>>>(xhi, xlo, w1thi, w1tlo, a1s, a1d,
                                         ghi, es, ed, N_NODES, INCH);
    aggregate_fused<<<(N_NODES + 3) / 4, 256, 0, stream>>>(ghi, csr, offsets,
                                                           es, ed, b1, h1hi, h1lo);
    // ---- layer 2 ----
    gemm_mfma<<<ggrid, 256, 0, stream>>>(h1hi, h1lo, w2thi, w2tlo, a2s, a2d,
                                         ghi, es, ed, N_NODES, NHD);
    aggregate_fused<<<(N_NODES + 3) / 4, 256, 0, stream>>>(ghi, csr, offsets,
                                                           es, ed, b2, h2hi, nullptr);

    // ---- pooling + MLP ----
    pool_sum_kernel<<<(N_NODES + PRB - 1) / PRB, 640, 0, stream>>>(xhi, h1hi, h2hi, batch, psums);
    mlp_kernel<<<NGRAPH / 8, 256, 0, stream>>>(psums, goff, W3, b3, W4, b4, out);
}

// Round 12
// 486.396 us; speedup vs baseline: 1.7563x; 1.0003x over previous
//
#include <hip/hip_runtime.h>
#include <cstdint>
#include <cstddef>

#define N_NODES 50000
#define M_PAD 50048    // 391 * 128, covers GEMM tile over-read
#define E_EDGES 800000
#define INCH 128
#define HID 64
#define HEADS 4
#define NHD 256      // HEADS*HID
#define NGRAPH 64
#define DCAT 640     // 128 + 256 + 256
#define NEG_SLOPE 0.2f

typedef __attribute__((ext_vector_type(8))) short bf16x8;
typedef __attribute__((ext_vector_type(4))) float f32x4;

// round-to-nearest-even fp32 -> bf16 bits
static __device__ inline unsigned short f2bf(float f) {
    unsigned int u = __float_as_uint(f);
    unsigned int r = (u + 0x7FFFu + ((u >> 16) & 1u)) >> 16;
    return (unsigned short)r;
}
static __device__ inline float bf2f(unsigned short b) {
    return __uint_as_float(((unsigned int)b) << 16);
}

// ---- fused preamble: hist + graph_offsets + psums-zero + hi/lo splits -------
#define W1N (INCH * NHD)            // 32768
#define W2N (NHD * NHD)             // 65536
#define XN  (N_NODES * INCH)        // 6.4M
#define HB  ((E_EDGES + 255) / 256)           // 3125 hist blocks
#define GB  ((N_NODES + 255) / 256)           // 196 graph_offsets blocks
#define PZB ((NGRAPH * DCAT + 255) / 256)     // 160 psums-zero blocks
#define SPB ((W1N + W2N + XN + 255) / 256)    // 25384 split blocks
#define PREPB (HB + GB + PZB + SPB)

__global__ void prep_kernel(
    const int* __restrict__ ei, const int* __restrict__ batch,
    const float* __restrict__ W1, const float* __restrict__ W2,
    const float* __restrict__ x,
    int* __restrict__ counts, int* __restrict__ goff,
    float* __restrict__ psums,
    unsigned short* __restrict__ w1thi, unsigned short* __restrict__ w1tlo,
    unsigned short* __restrict__ w2thi, unsigned short* __restrict__ w2tlo,
    unsigned short* __restrict__ xhi, unsigned short* __restrict__ xlo)
{
    const int b = blockIdx.x;
    if (b < HB) {                               // ---- histogram of dst ----
        const int e = b * 256 + threadIdx.x;
        if (e < E_EDGES) atomicAdd(&counts[ei[E_EDGES + e]], 1);
        return;
    }
    if (b < HB + GB) {                          // ---- graph offsets ----
        const int n = (b - HB) * 256 + threadIdx.x;
        if (n >= N_NODES) return;
        const int bb = batch[n];
        const int bp = (n == 0) ? -1 : batch[n - 1];
        for (int g = bp + 1; g <= bb; ++g) goff[g] = n;
        if (n == N_NODES - 1)
            for (int g = bb + 1; g <= NGRAPH; ++g) goff[g] = N_NODES;
        return;
    }
    if (b < HB + GB + PZB) {                    // ---- zero psums ----
        const int i = (b - HB - GB) * 256 + threadIdx.x;
        if (i < NGRAPH * DCAT) psums[i] = 0.f;
        return;
    }
    // ---- hi/lo splits: W1^T, W2^T, x ----
    const int i = (b - HB - GB - PZB) * 256 + threadIdx.x;
    float v; unsigned short* dhi; unsigned short* dlo; int idx;
    if (i < W1N) {
        const int n = i / INCH, k = i - n * INCH;
        v = W1[(size_t)k * NHD + n]; dhi = w1thi; dlo = w1tlo; idx = i;
    } else if (i < W1N + W2N) {
        const int j = i - W1N;
        const int n = j / NHD, k = j - n * NHD;
        v = W2[(size_t)k * NHD + n]; dhi = w2thi; dlo = w2tlo; idx = j;
    } else {
        const int j = i - W1N - W2N;
        if (j >= XN) return;
        v = x[j]; dhi = xhi; dlo = xlo; idx = j;
    }
    const unsigned short h = f2bf(v);
    dhi[idx] = h;
    dlo[idx] = f2bf(v - bf2f(h));
}

// ------- MFMA GEMM v3: full-N tile. Cb[M,256] = (Ahi+Alo) @ (Bhi+Blo) --------
// Block: 128 rows x 256 cols (whole N), so the A tile is fetched exactly ONCE
// per GEMM (halves A traffic vs 2 col-blocks). 4 waves of 64x128; GK=32.
// LDS 61.4 KB -> still 2 blocks/CU. b-frags loaded per-j to cap VGPRs.
#define GK 32
#define LDA 40   // LDS row stride (80B: b128 reads 2-way aliasing = free)

__global__ __launch_bounds__(256, 2) void gemm_mfma(
    const unsigned short* __restrict__ Athi,
    const unsigned short* __restrict__ Atlo,
    const unsigned short* __restrict__ Bthi,
    const unsigned short* __restrict__ Btlo,
    const float* __restrict__ asrc, const float* __restrict__ adst,
    unsigned short* __restrict__ Cb, float* __restrict__ es,
    float* __restrict__ ed, int M, int K)
{
    __shared__ unsigned short Ahi[128 * LDA];
    __shared__ unsigned short Alo[128 * LDA];
    __shared__ unsigned short Bhi[256 * LDA];
    __shared__ unsigned short Blo[256 * LDA];

    const int t    = threadIdx.x;
    const int row0 = blockIdx.x * 128;
    const int wave = t >> 6, lane = t & 63;
    const int wr  = (wave >> 1) * 64;     // wave row offset (0/64)
    const int wc2 = (wave & 1) * 128;     // wave col offset (0/128)
    const int m16 = lane & 15, quad = lane >> 4;

    f32x4 acc[4][8];
#pragma unroll
    for (int i = 0; i < 4; ++i)
#pragma unroll
        for (int j = 0; j < 8; ++j) acc[i][j] = (f32x4){0.f, 0.f, 0.f, 0.f};

    for (int k0 = 0; k0 < K; k0 += GK) {
        // ---- stage A: 128 x 32 (hi+lo) ----
#pragma unroll
        for (int i = 0; i < 2; ++i) {
            const int seg = t + i * 256;         // 512 segs of 8 bf16
            const int r = seg >> 2, p = (seg & 3) * 8;
            const size_t ga = (size_t)(row0 + r) * K + k0 + p;
            *(int4*)(&Ahi[r * LDA + p]) = *(const int4*)(Athi + ga);
            *(int4*)(&Alo[r * LDA + p]) = *(const int4*)(Atlo + ga);
        }
        // ---- stage B: 256 x 32 (hi+lo) ----
#pragma unroll
        for (int i = 0; i < 4; ++i) {
            const int seg = t + i * 256;         // 1024 segs of 8 bf16
            const int r = seg >> 2, p = (seg & 3) * 8;
            const size_t gb = (size_t)r * K + k0 + p;
            *(int4*)(&Bhi[r * LDA + p]) = *(const int4*)(Bthi + gb);
            *(int4*)(&Blo[r * LDA + p]) = *(const int4*)(Btlo + gb);
        }
        __syncthreads();

        bf16x8 afh[4], afl[4];
#pragma unroll
        for (int i = 0; i < 4; ++i) {
            const int r = wr + i * 16 + m16;
            afh[i] = *(const bf16x8*)(&Ahi[r * LDA + quad * 8]);
            afl[i] = *(const bf16x8*)(&Alo[r * LDA + quad * 8]);
        }
#pragma unroll
        for (int j = 0; j < 8; ++j) {
            const int n = wc2 + j * 16 + m16;
            const bf16x8 bh = *(const bf16x8*)(&Bhi[n * LDA + quad * 8]);
            const bf16x8 bl = *(const bf16x8*)(&Blo[n * LDA + quad * 8]);
#pragma unroll
            for (int i = 0; i < 4; ++i) {
                acc[i][j] = __builtin_amdgcn_mfma_f32_16x16x32_bf16(afh[i], bh, acc[i][j], 0, 0, 0);
                acc[i][j] = __builtin_amdgcn_mfma_f32_16x16x32_bf16(afh[i], bl, acc[i][j], 0, 0, 0);
                acc[i][j] = __builtin_amdgcn_mfma_f32_16x16x32_bf16(afl[i], bh, acc[i][j], 0, 0, 0);
            }
        }
        __syncthreads();
    }

    // ---- epilogue 1: bf16 C store (C/D layout col=lane&15, row=quad*4+reg)
#pragma unroll
    for (int i = 0; i < 4; ++i)
#pragma unroll
        for (int reg = 0; reg < 4; ++reg) {
            const int r = row0 + wr + i * 16 + quad * 4 + reg;
            if (r < M) {
#pragma unroll
                for (int j = 0; j < 8; ++j)
                    Cb[(size_t)r * NHD + wc2 + j * 16 + m16] = f2bf(acc[i][j][reg]);
            }
        }

    // ---- epilogue 2: fused attention coefficients, 2 heads per wave ----
    const int hbase = wc2 >> 6;     // heads hbase, hbase+1
    float a_s0[4], a_d0[4], a_s1[4], a_d1[4];
#pragma unroll
    for (int j = 0; j < 4; ++j) {
        a_s0[j] = asrc[hbase * HID + j * 16 + m16];
        a_d0[j] = adst[hbase * HID + j * 16 + m16];
        a_s1[j] = asrc[(hbase + 1) * HID + j * 16 + m16];
        a_d1[j] = adst[(hbase + 1) * HID + j * 16 + m16];
    }
#pragma unroll
    for (int i = 0; i < 4; ++i)
#pragma unroll
        for (int reg = 0; reg < 4; ++reg) {
            float ps0 = 0.f, pd0 = 0.f, ps1 = 0.f, pd1 = 0.f;
#pragma unroll
            for (int j = 0; j < 4; ++j) {
                const float v0 = acc[i][j][reg];
                const float v1 = acc[i][j + 4][reg];
                ps0 += v0 * a_s0[j];
                pd0 += v0 * a_d0[j];
                ps1 += v1 * a_s1[j];
                pd1 += v1 * a_d1[j];
            }
#pragma unroll
            for (int off = 1; off < 16; off <<= 1) {
                ps0 += __shfl_xor(ps0, off, 64);
                pd0 += __shfl_xor(pd0, off, 64);
                ps1 += __shfl_xor(ps1, off, 64);
                pd1 += __shfl_xor(pd1, off, 64);
            }
            if (m16 == 0) {
                const int r = row0 + wr + i * 16 + quad * 4 + reg;
                if (r < M) {
                    es[r * HEADS + hbase]     = ps0;
                    ed[r * HEADS + hbase]     = pd0;
                    es[r * HEADS + hbase + 1] = ps1;
                    ed[r * HEADS + hbase + 1] = pd1;
                }
            }
        }
}

// ------------------------------ CSR scan ------------------------------------
#define SBLK 1024
#define NSCB ((N_NODES + SBLK - 1) / SBLK)   // 49

__global__ __launch_bounds__(1024) void scan_local_kernel(
    const int* __restrict__ counts, int* __restrict__ offsets,
    int* __restrict__ bsum)
{
    __shared__ int tmp[SBLK];
    const int t = threadIdx.x;
    const int i = blockIdx.x * SBLK + t;
    const int v = (i < N_NODES) ? counts[i] : 0;
    tmp[t] = v;
    __syncthreads();
    for (int off = 1; off < SBLK; off <<= 1) {
        const int u = (t >= off) ? tmp[t - off] : 0;
        __syncthreads();
        tmp[t] += u;
        __syncthreads();
    }
    if (i < N_NODES) offsets[i] = tmp[t] - v;    // local exclusive prefix
    if (t == SBLK - 1) bsum[blockIdx.x] = tmp[t];
}

__global__ __launch_bounds__(1024) void scan_final_kernel(
    int* __restrict__ offsets, int* __restrict__ cursor,
    const int* __restrict__ bsum)
{
    __shared__ int base_sh;
    const int b = blockIdx.x;
    if (threadIdx.x == 0) {
        int s = 0;
        for (int j = 0; j < b; ++j) s += bsum[j];
        base_sh = s;
    }
    __syncthreads();
    const int i = b * SBLK + threadIdx.x;
    if (i < N_NODES) {
        const int v = offsets[i] + base_sh;
        offsets[i] = v;
        cursor[i]  = v;
    }
    if (b == 0 && threadIdx.x == 0) offsets[N_NODES] = E_EDGES;
}

// scatter: csr holds the SRC node id directly
__global__ void scatter_kernel(const int* __restrict__ ei, int* __restrict__ cursor,
                               int* __restrict__ csr)
{
    const int e = blockIdx.x * 256 + threadIdx.x;
    if (e >= E_EDGES) return;
    const int s = ei[e];
    const int d = ei[E_EDGES + e];
    const int pos = atomicAdd(&cursor[d], 1);
    csr[pos] = s;
}

// ------- fused softmax + aggregation: one wave per dst node ------------------
__global__ __launch_bounds__(256) void aggregate_fused(
    const unsigned short* __restrict__ hb, const int* __restrict__ csr,
    const int* __restrict__ offsets,
    const float* __restrict__ es, const float* __restrict__ ed,
    const float* __restrict__ bias, unsigned short* __restrict__ outhi,
    unsigned short* __restrict__ outlo)
{
    const int wid  = threadIdx.x >> 6;
    const int lane = threadIdx.x & 63;
    const int node = blockIdx.x * 4 + wid;
    if (node >= N_NODES) return;
    const int head = lane >> 4;          // col = lane*4 -> head = col/64
    const int col  = lane * 4;
    const int sub  = lane & 15;          // edge slot within 16-edge chunk

    const float edc = ed[node * 4 + head];
    const int beg = offsets[node], end = offsets[node + 1];

    float4 acc = make_float4(0.f, 0.f, 0.f, 0.f);
    float dsum = 0.f;

    int base = beg;
    int m_cur = min(16, end - base);
    int s_cur = 0; float w_cur = 0.f;
    if (base < end && sub < m_cur) {
        s_cur = csr[base + sub];
        float u = es[s_cur * 4 + head] + edc;
        u = u > 0.f ? u : NEG_SLOPE * u;
        w_cur = expf(u);
    }

    while (base < end) {
        const int base_n = base + 16;
        const int m_nxt = min(16, end - base_n);
        int s_nxt = 0; float w_nxt = 0.f;
        if (base_n < end && sub < m_nxt) {
            s_nxt = csr[base_n + sub];
            float u = es[s_nxt * 4 + head] + edc;
            u = u > 0.f ? u : NEG_SLOPE * u;
            w_nxt = expf(u);
        }
        if (m_cur == 16) {
#pragma unroll
            for (int i = 0; i < 16; ++i) {
                const int   s = (int)__builtin_amdgcn_readlane((unsigned)s_cur, i);
                const float w = __shfl(w_cur, (lane & 48) + i, 64);
                const ushort4 v = *(const ushort4*)(hb + (size_t)s * NHD + col);
                acc.x += w * bf2f(v.x);
                acc.y += w * bf2f(v.y);
                acc.z += w * bf2f(v.z);
                acc.w += w * bf2f(v.w);
                dsum += w;
            }
        } else {
            for (int i = 0; i < m_cur; ++i) {
                const int   s = __shfl(s_cur, i, 64);
                const float w = __shfl(w_cur, (lane & 48) + i, 64);
                const ushort4 v = *(const ushort4*)(hb + (size_t)s * NHD + col);
                acc.x += w * bf2f(v.x);
                acc.y += w * bf2f(v.y);
                acc.z += w * bf2f(v.z);
                acc.w += w * bf2f(v.w);
                dsum += w;
            }
        }
        s_cur = s_nxt; w_cur = w_nxt; m_cur = m_nxt; base = base_n;
    }

    const float inv = 1.0f / (dsum + 1e-16f);
    const float4 bb = *(const float4*)(bias + col);
    float4 o;
    o.x = fmaxf(acc.x * inv + bb.x, 0.f);
    o.y = fmaxf(acc.y * inv + bb.y, 0.f);
    o.z = fmaxf(acc.z * inv + bb.z, 0.f);
    o.w = fmaxf(acc.w * inv + bb.w, 0.f);
    ushort4 oh;
    oh.x = f2bf(o.x); oh.y = f2bf(o.y); oh.z = f2bf(o.z); oh.w = f2bf(o.w);
    *(ushort4*)(outhi + (size_t)node * NHD + col) = oh;
    if (outlo) {
        ushort4 ol;
        ol.x = f2bf(o.x - bf2f(oh.x));
        ol.y = f2bf(o.y - bf2f(oh.y));
        ol.z = f2bf(o.z - bf2f(oh.z));
        ol.w = f2bf(o.w - bf2f(oh.w));
        *(ushort4*)(outlo + (size_t)node * NHD + col) = ol;
    }
}

// ------------------------------ pooling (all-bf16 sources) -------------------
#define PRB 128

__global__ __launch_bounds__(640) void pool_sum_kernel(
    const unsigned short* __restrict__ xhi, const unsigned short* __restrict__ h1b,
    const unsigned short* __restrict__ h2b, const int* __restrict__ batch,
    float* __restrict__ sums)
{
    __shared__ int bsh[PRB];
    const int c  = threadIdx.x;            // 0..639
    const int r0 = blockIdx.x * PRB;
    const int r1 = min(N_NODES, r0 + PRB);
    const int nr = r1 - r0;
    if (c < nr) bsh[c] = batch[r0 + c];
    __syncthreads();

    const unsigned short* srcb; int ld, cc;
    if (c < INCH)            { srcb = xhi; ld = INCH; cc = c; }
    else if (c < INCH + NHD) { srcb = h1b; ld = NHD;  cc = c - INCH; }
    else                     { srcb = h2b; ld = NHD;  cc = c - INCH - NHD; }

    float sum = 0.f;
    int g = bsh[0];
    for (int i = 0; i < nr; ++i) {
        const int gb = bsh[i];
        if (gb != g) {
            atomicAdd(&sums[g * DCAT + c], sum);
            sum = 0.f;
            g = gb;
        }
        sum += bf2f(srcb[(size_t)(r0 + i) * ld + cc]);
    }
    atomicAdd(&sums[g * DCAT + c], sum);
}

// --------------- MLP head: 8 graphs per block, 8 blocks ----------------------
__global__ __launch_bounds__(256) void mlp_kernel(
    const float* __restrict__ psums, const int* __restrict__ goff,
    const float* __restrict__ W3, const float* __restrict__ b3,
    const float* __restrict__ W4, const float* __restrict__ b4,
    float* __restrict__ out)
{
    const int g0 = blockIdx.x * 8;
    __shared__ float p[8][DCAT];    // 20 KB
    __shared__ float hm[8][256];    // 8 KB
    for (int idx = threadIdx.x; idx < 8 * DCAT; idx += 256) {
        const int gg = idx / DCAT, i = idx - gg * DCAT;
        const int g = g0 + gg;
        const float inv = 1.0f / fmaxf((float)(goff[g + 1] - goff[g]), 1.0f);
        p[gg][i] = psums[(size_t)g * DCAT + i] * inv;
    }
    __syncthreads();
    const int c = threadIdx.x;
    float acc[8];
#pragma unroll
    for (int gg = 0; gg < 8; ++gg) acc[gg] = b3[c];
    for (int k = 0; k < DCAT; ++k) {
        const float w = W3[(size_t)k * 256 + c];
#pragma unroll
        for (int gg = 0; gg < 8; ++gg) acc[gg] += p[gg][k] * w;
    }
#pragma unroll
    for (int gg = 0; gg < 8; ++gg) hm[gg][c] = fmaxf(acc[gg], 0.f);
    __syncthreads();
    const int c2 = threadIdx.x & 127;
    const int gh = (threadIdx.x >> 7) * 4;   // 0 or 4
    float a2[4];
#pragma unroll
    for (int j = 0; j < 4; ++j) a2[j] = b4[c2];
    for (int k = 0; k < 256; ++k) {
        const float w = W4[(size_t)k * 128 + c2];
#pragma unroll
        for (int j = 0; j < 4; ++j) a2[j] += hm[gh + j][k] * w;
    }
#pragma unroll
    for (int j = 0; j < 4; ++j)
        out[(size_t)(g0 + gh + j) * 128 + c2] = a2[j];
}

// ------------------------------ launch --------------------------------------
extern "C" void kernel_launch(void* const* d_in, const int* in_sizes, int n_in,
                              void* d_out, int out_size, void* d_ws, size_t ws_size,
                              hipStream_t stream)
{
    const float* x     = (const float*)d_in[0];
    const int*   ei    = (const int*)d_in[1];
    const int*   batch = (const int*)d_in[2];
    const float* W1    = (const float*)d_in[3];
    const float* a1s   = (const float*)d_in[4];
    const float* a1d   = (const float*)d_in[5];
    const float* b1    = (const float*)d_in[6];
    const float* W2    = (const float*)d_in[7];
    const float* a2s   = (const float*)d_in[8];
    const float* a2d   = (const float*)d_in[9];
    const float* b2    = (const float*)d_in[10];
    const float* W3    = (const float*)d_in[11];
    const float* b3    = (const float*)d_in[12];
    const float* W4    = (const float*)d_in[13];
    const float* b4    = (const float*)d_in[14];
    float* out = (float*)d_out;

    // workspace carve
    size_t off = 0;
    auto carve = [&](size_t bytes) -> void* {
        void* p = (char*)d_ws + off;
        off = (off + bytes + 255) & ~(size_t)255;
        return p;
    };
    unsigned short* xhi   = (unsigned short*)carve((size_t)M_PAD * INCH * 2);
    unsigned short* xlo   = (unsigned short*)carve((size_t)M_PAD * INCH * 2);
    unsigned short* ghi   = (unsigned short*)carve((size_t)N_NODES * NHD * 2);  // GEMM out (gather src)
    unsigned short* h1hi  = (unsigned short*)carve((size_t)M_PAD * NHD * 2);
    unsigned short* h1lo  = (unsigned short*)carve((size_t)M_PAD * NHD * 2);
    unsigned short* h2hi  = (unsigned short*)carve((size_t)N_NODES * NHD * 2);
    float* es     = (float*)carve((size_t)N_NODES * HEADS * 4);
    float* ed     = (float*)carve((size_t)N_NODES * HEADS * 4);
    float* psums  = (float*)carve((size_t)NGRAPH * DCAT * 4);
    int*   counts  = (int*)carve((size_t)N_NODES * 4);
    int*   offsets = (int*)carve((size_t)(N_NODES + 1) * 4);
    int*   cursor  = (int*)carve((size_t)N_NODES * 4);
    int*   csr     = (int*)carve((size_t)E_EDGES * 4);
    int*   goff    = (int*)carve((size_t)(NGRAPH + 1) * 4);
    int*   bsum    = (int*)carve((size_t)NSCB * 4);
    unsigned short* w1thi = (unsigned short*)carve((size_t)NHD * INCH * 2);
    unsigned short* w1tlo = (unsigned short*)carve((size_t)NHD * INCH * 2);
    unsigned short* w2thi = (unsigned short*)carve((size_t)NHD * NHD * 2);
    unsigned short* w2tlo = (unsigned short*)carve((size_t)NHD * NHD * 2);

    const int egrid = (E_EDGES + 255) / 256;

    // ---- preamble: histogram + graph offsets + psums zero + splits ----
    hipMemsetAsync(counts, 0, (size_t)N_NODES * 4, stream);
    prep_kernel<<<PREPB, 256, 0, stream>>>(ei, batch, W1, W2, x,
                                           counts, goff, psums,
                                           w1thi, w1tlo, w2thi, w2tlo, xhi, xlo);
    scan_local_kernel<<<NSCB, SBLK, 0, stream>>>(counts, offsets, bsum);
    scan_final_kernel<<<NSCB, SBLK, 0, stream>>>(offsets, cursor, bsum);
    scatter_kernel<<<egrid, 256, 0, stream>>>(ei, cursor, csr);

    const int ggrid = M_PAD / 128;   // 391, full-N tile

    // ---- layer 1 ----
    gemm_mfma<<<ggrid, 256, 0, stream>>>(xhi, xlo, w1thi, w1tlo, a1s, a1d,
                                         ghi, es, ed, N_NODES, INCH);
    aggregate_fused<<<(N_NODES + 3) / 4, 256, 0, stream>>>(ghi, csr, offsets,
                                                           es, ed, b1, h1hi, h1lo);
    // ---- layer 2 ----
    gemm_mfma<<<ggrid, 256, 0, stream>>>(h1hi, h1lo, w2thi, w2tlo, a2s, a2d,
                                         ghi, es, ed, N_NODES, NHD);
    aggregate_fused<<<(N_NODES + 3) / 4, 256, 0, stream>>>(ghi, csr, offsets,
                                                           es, ed, b2, h2hi, nullptr);

    // ---- pooling + MLP ----
    pool_sum_kernel<<<(N_NODES + PRB - 1) / PRB, 640, 0, stream>>>(xhi, h1hi, h2hi, batch, psums);
    mlp_kernel<<<NGRAPH / 8, 256, 0, stream>>>(psums, goff, W3, b3, W4, b4, out);
}